// Round 19
// baseline (469.945 us; speedup 1.0000x reference)
//
#include <hip/hip_runtime.h>
#include <hip/hip_bf16.h>
#include <math.h>

#define B_SZ 4
#define CDIM 512
#define NPIX 4096
#define EPSN 1e-5f

typedef unsigned short u16;
typedef __attribute__((ext_vector_type(8))) short bf16x8;
typedef __attribute__((ext_vector_type(4))) float f32x4;
typedef __attribute__((ext_vector_type(16))) float f32x16;

#define MFMA_BF16 __builtin_amdgcn_mfma_f32_16x16x32_bf16
#define MFMA32    __builtin_amdgcn_mfma_f32_32x32x16_bf16

// async global->LDS DMA, 16B per lane; LDS dest = wave-uniform base + lane*16
#define GLD16(gp, lp) __builtin_amdgcn_global_load_lds( \
    (const __attribute__((address_space(1))) void*)(gp), \
    (__attribute__((address_space(3))) void*)(lp), 16, 0, 0)

static __device__ __forceinline__ float bf2f(u16 u) {
    return __uint_as_float(((unsigned)u) << 16);
}
static __device__ __forceinline__ u16 f2bf(float f) {
    unsigned u = __float_as_uint(f);
    unsigned r = (u + 0x7FFFu + ((u >> 16) & 1u)) >> 16;
    return (u16)r;
}

// ---------------------------------------------------------------------------
// transpose3b: z = gb*3 + which; source fp32 [CDIM][NPIX] (global batch
// bg0+gb) -> XT slab entry z, bf16 [NPIX][CDIM].
// ---------------------------------------------------------------------------
__global__ __launch_bounds__(256) void transpose3b(const float* __restrict__ X0,
    const float* __restrict__ X1, const float* __restrict__ X2,
    u16* __restrict__ XTbase, int bg0)
{
    const int z = blockIdx.z;
    const int gb = z / 3, which = z % 3;
    const size_t TBe = (size_t)CDIM * NPIX;
    const float* X = (which == 0 ? X0 : which == 1 ? X1 : X2) + (size_t)(bg0 + gb) * TBe;
    u16* XT = XTbase + (size_t)z * TBe;

    __shared__ float T[64][65];
    const int t = threadIdx.x;
    const int n0 = blockIdx.x * 64, c0 = blockIdx.y * 64;
    #pragma unroll
    for (int p = 0; p < 4; p++) {
        int c_l = (t >> 4) + p * 16;
        int n_l = (t & 15) * 4;
        float4 v = *(const float4*)&X[(size_t)(c0 + c_l) * NPIX + n0 + n_l];
        T[c_l][n_l+0] = v.x; T[c_l][n_l+1] = v.y; T[c_l][n_l+2] = v.z; T[c_l][n_l+3] = v.w;
    }
    __syncthreads();
    #pragma unroll
    for (int p = 0; p < 4; p++) {
        int n_l = t >> 2;
        int cs  = (t & 3) * 4 + p * 16;
        ushort4 r;
        r.x = f2bf(T[cs+0][n_l]); r.y = f2bf(T[cs+1][n_l]);
        r.z = f2bf(T[cs+2][n_l]); r.w = f2bf(T[cs+3][n_l]);
        *(ushort4*)&XT[(size_t)(n0 + n_l) * CDIM + c0 + cs] = r;
    }
}

// ---------------------------------------------------------------------------
// conv3b: z = gb*3 + which. D[o][n] = bias[o] + sum_c W[o][c]*XT[n][c].
// which<2: store D^T to (FT|GT)+gb*TB ([n][CDIM]); which==2: Hb+gb*TB.
// ---------------------------------------------------------------------------
__global__ __launch_bounds__(256) void conv3b(const u16* __restrict__ XTbase,
    const float* __restrict__ W0, const float* __restrict__ W1, const float* __restrict__ W2,
    const float* __restrict__ b0, const float* __restrict__ b1, const float* __restrict__ b2,
    u16* __restrict__ FTb, u16* __restrict__ GTb, u16* __restrict__ Hbb)
{
    const int z = blockIdx.z;
    const int gb = z / 3, which = z % 3;
    const size_t TBe = (size_t)CDIM * NPIX;
    const u16* XT = XTbase + (size_t)z * TBe;
    const float* W = which == 0 ? W0 : which == 1 ? W1 : W2;
    const float* bias = which == 0 ? b0 : which == 1 ? b1 : b2;

    const int t = threadIdx.x;
    const int lane = t & 63, wv = t >> 6;
    const int wr = wv >> 1, wc = wv & 1;
    const int n0 = blockIdx.x * 64;
    const int o0 = blockIdx.y * 64;
    const int g = lane >> 4, li = lane & 15;

    __shared__ short Aw[64][40];
    __shared__ short Bx[64][40];

    f32x4 acc[2][2] = {};
    const int srow = t >> 2, sseg = (t & 3) * 8;

    float4 w0 = *(const float4*)&W[(size_t)(o0 + srow) * CDIM + sseg];
    float4 w1 = *(const float4*)&W[(size_t)(o0 + srow) * CDIM + sseg + 4];
    bf16x8 bv = *(const bf16x8*)&XT[(size_t)(n0 + srow) * CDIM + sseg];

    for (int kb = 0; kb < CDIM; kb += 32) {
        bf16x8 wa;
        wa[0] = (short)f2bf(w0.x); wa[1] = (short)f2bf(w0.y);
        wa[2] = (short)f2bf(w0.z); wa[3] = (short)f2bf(w0.w);
        wa[4] = (short)f2bf(w1.x); wa[5] = (short)f2bf(w1.y);
        wa[6] = (short)f2bf(w1.z); wa[7] = (short)f2bf(w1.w);
        __syncthreads();
        *(bf16x8*)&Aw[srow][sseg] = wa;
        *(bf16x8*)&Bx[srow][sseg] = bv;
        if (kb + 32 < CDIM) {
            w0 = *(const float4*)&W[(size_t)(o0 + srow) * CDIM + kb + 32 + sseg];
            w1 = *(const float4*)&W[(size_t)(o0 + srow) * CDIM + kb + 32 + sseg + 4];
            bv = *(const bf16x8*)&XT[(size_t)(n0 + srow) * CDIM + kb + 32 + sseg];
        }
        __syncthreads();
        bf16x8 a[2], b[2];
        #pragma unroll
        for (int i = 0; i < 2; i++) a[i] = *(const bf16x8*)&Aw[wr*32 + i*16 + li][g*8];
        #pragma unroll
        for (int j = 0; j < 2; j++) b[j] = *(const bf16x8*)&Bx[wc*32 + j*16 + li][g*8];
        #pragma unroll
        for (int i = 0; i < 2; i++)
            #pragma unroll
            for (int j = 0; j < 2; j++)
                acc[i][j] = MFMA_BF16(a[i], b[j], acc[i][j], 0, 0, 0);
    }

    #pragma unroll
    for (int i = 0; i < 2; i++) {
        const int orow = o0 + wr*32 + i*16 + 4*g;
        float4 bs = *(const float4*)&bias[orow];
        #pragma unroll
        for (int j = 0; j < 2; j++) {
            const int ncol = n0 + wc*32 + j*16 + li;
            if (which < 2) {
                u16* Y = (which == 0 ? FTb : GTb) + (size_t)gb * TBe;
                ushort4 r;
                r.x = f2bf(acc[i][j][0] + bs.x);
                r.y = f2bf(acc[i][j][1] + bs.y);
                r.z = f2bf(acc[i][j][2] + bs.z);
                r.w = f2bf(acc[i][j][3] + bs.w);
                *(ushort4*)&Y[(size_t)ncol * CDIM + orow] = r;
            } else {
                u16* Y2 = Hbb + (size_t)gb * TBe;
                const float bb[4] = { bs.x, bs.y, bs.z, bs.w };
                #pragma unroll
                for (int r = 0; r < 4; r++)
                    Y2[(size_t)(orow + r) * NPIX + ncol] = f2bf(acc[i][j][r] + bb[r]);
            }
        }
    }
}

// ---------------------------------------------------------------------------
// sq_h: H2[i] = bf16( bf2f(H[i])^2 )  — precompute so pv needs no VALU sq.
// ---------------------------------------------------------------------------
__global__ __launch_bounds__(256) void sq_h(const u16* __restrict__ H,
    u16* __restrict__ H2, size_t total8)
{
    size_t i = (size_t)blockIdx.x * 256 + threadIdx.x;
    if (i < total8) {
        bf16x8 v = *(const bf16x8*)&H[i * 8];
        bf16x8 o;
        #pragma unroll
        for (int e = 0; e < 8; e++) {
            float f = bf2f((u16)v[e]);
            o[e] = (short)f2bf(f * f);
        }
        *(bf16x8*)&H2[i * 8] = o;
    }
}

// ---------------------------------------------------------------------------
// norm2b: blockIdx.y = gb*2 + z. z=0: Fn[gb][n], rs[gb][n]=0 ; z=1: Gn[gb][n]
// ---------------------------------------------------------------------------
__global__ __launch_bounds__(256) void norm2b(const u16* __restrict__ FT,
    const u16* __restrict__ GT, float* __restrict__ Fn, float* __restrict__ Gn,
    float* __restrict__ rs)
{
    const int gb = blockIdx.y >> 1, z = blockIdx.y & 1;
    const size_t TBe = (size_t)CDIM * NPIX;
    const int n = blockIdx.x * 256 + threadIdx.x;
    const u16* row = ((z ? GT : FT) + (size_t)gb * TBe) + (size_t)n * CDIM;
    float s = 0.f;
    for (int c = 0; c < CDIM; c += 8) {
        bf16x8 v = *(const bf16x8*)&row[c];
        #pragma unroll
        for (int e = 0; e < 8; e++) { float f = bf2f((u16)v[e]); s += f * f; }
    }
    ((z ? Gn : Fn) + (size_t)gb * NPIX)[n] = sqrtf(s);
    if (!z) rs[(size_t)gb * NPIX + n] = 0.f;
}

// ---------------------------------------------------------------------------
// s_gemm128: S[nl][m] = bf16(relu(dot/((Fn+e)(Gn+e)) + 1)), + rowsum atomics.
// 128x128 tile, 4 waves (2x2 of 64x64), K-step 32, gld_lds DMA staging with
// source-side swizzle, T4 counted-vmcnt sync. (unchanged from r18)
// ---------------------------------------------------------------------------
__global__ __launch_bounds__(256) void s_gemm128(const u16* __restrict__ FTb,
    const u16* __restrict__ GTb, const float* __restrict__ Fnb, const float* __restrict__ Gnb,
    u16* __restrict__ Sbase, float* __restrict__ rsb, int strip_base, int swz,
    size_t s_stride)
{
    const int gb = blockIdx.y;
    const size_t TBe = (size_t)CDIM * NPIX;
    const u16* FT = FTb + (size_t)gb * TBe;
    const u16* GT = GTb + (size_t)gb * TBe;
    const float* Fn = Fnb + (size_t)gb * NPIX;
    const float* Gn = Gnb + (size_t)gb * NPIX;
    u16* S = Sbase + (size_t)gb * s_stride;
    float* rs = rsb + (size_t)gb * NPIX;

    const int t = threadIdx.x;
    const int lane = t & 63, wv = t >> 6;
    const int wr = wv >> 1, wc = wv & 1;

    int mm, nn;
    if (swz) {            // (ns/128) % 8 == 0
        const int xk = blockIdx.x & 7, q = blockIdx.x >> 3;
        mm = q & 31;                      // NPIX/128 == 32
        nn = (q >> 5) * 8 + xk;
    } else {
        mm = blockIdx.x & 31;
        nn = blockIdx.x >> 5;
    }
    const int m0  = mm * 128;
    const int nl0 = nn * 128;
    const int ng0 = strip_base + nl0;
    const int g = lane >> 4, li = lane & 15;

    __shared__ short Cs[2][128][64];   // 32 KB total

    f32x4 acc[4][4] = {};

    const int lr = lane >> 3, lq = lane & 7;

    #define SG_STAGE(BUF, KB)                                                  \
    {                                                                          \
        _Pragma("unroll")                                                      \
        for (int ch = 0; ch < 4; ch++) {                                       \
            const int r0 = wv*32 + ch*8;                                       \
            const int r  = r0 + lr;                                            \
            const int c  = lq ^ (r & 7);                                       \
            const u16* gp = (c < 4)                                            \
                ? &FT[(size_t)(ng0 + r) * CDIM + (KB) + c*8]                   \
                : &GT[(size_t)(m0  + r) * CDIM + (KB) + (c-4)*8];              \
            GLD16(gp, &Cs[BUF][r0][0]);                                        \
        }                                                                      \
    }

    SG_STAGE(0, 0);

    int buf = 0;
    for (int kb = 0; kb < CDIM; kb += 32) {
        if (kb + 32 < CDIM) {
            SG_STAGE(buf ^ 1, kb + 32);
            asm volatile("s_waitcnt vmcnt(4)" ::: "memory");   // tile t landed
        } else {
            asm volatile("s_waitcnt vmcnt(0)" ::: "memory");
        }
        __builtin_amdgcn_s_barrier();
        bf16x8 a[4], b[4];
        #pragma unroll
        for (int i = 0; i < 4; i++) {
            const int row = wr*64 + i*16 + li;
            a[i] = *(const bf16x8*)&Cs[buf][row][(g ^ (row & 7)) * 8];
        }
        #pragma unroll
        for (int j = 0; j < 4; j++) {
            const int row = wc*64 + j*16 + li;
            b[j] = *(const bf16x8*)&Cs[buf][row][((4 + g) ^ (row & 7)) * 8];
        }
        #pragma unroll
        for (int i = 0; i < 4; i++)
            #pragma unroll
            for (int j = 0; j < 4; j++)
                acc[i][j] = MFMA_BF16(a[i], b[j], acc[i][j], 0, 0, 0);
        __builtin_amdgcn_s_barrier();      // reads done -> next issue may reuse buf
        buf ^= 1;
    }
    #undef SG_STAGE

    float gi[4];
    #pragma unroll
    for (int j = 0; j < 4; j++) gi[j] = 1.f / (Gn[m0 + wc*64 + j*16 + li] + EPSN);
    #pragma unroll
    for (int i = 0; i < 4; i++) {
        const int nl = nl0 + wr*64 + i*16 + 4*g;
        float4 fn4 = *(const float4*)&Fn[strip_base + nl];
        const float fi4[4] = { 1.f/(fn4.x + EPSN), 1.f/(fn4.y + EPSN),
                               1.f/(fn4.z + EPSN), 1.f/(fn4.w + EPSN) };
        float ps[4] = {0.f, 0.f, 0.f, 0.f};
        #pragma unroll
        for (int j = 0; j < 4; j++) {
            const int m = m0 + wc*64 + j*16 + li;
            #pragma unroll
            for (int r = 0; r < 4; r++) {
                float v = fmaxf(acc[i][j][r] * fi4[r] * gi[j] + 1.f, 0.f);
                u16 hv = f2bf(v);
                S[(size_t)(nl + r) * NPIX + m] = hv;
                ps[r] += bf2f(hv);
            }
        }
        #pragma unroll
        for (int r = 0; r < 4; r++) {
            float p = ps[r];
            p += __shfl_xor(p, 1);
            p += __shfl_xor(p, 2);
            p += __shfl_xor(p, 4);
            p += __shfl_xor(p, 8);
            if (li == 0) atomicAdd(&rs[strip_base + nl + r], p);
        }
    }
}

// ---------------------------------------------------------------------------
// pv128: mean/msq via MFMA 32x32x16, H^2 STAGED (not recomputed — r18 showed
// sq_bf16x8 put ~320 VALU cyc/wave-phase against 128 MFMA cyc; VALU was the
// binding pipe at MfmaUtil 42 / VALUBusy 47).
// Tile 128c x 128n, 4 waves of 64x64. K-step 32, 3 streams per 256B LDS row:
// [H slots 0-3 | H2 4-7 | S 8-11 | dup-H 12-15], phys slot = logical ^
// (row&15) (the proven involution; dead slots sourced from hot H rows).
// Counted vmcnt(8), raw barriers, 64 KB LDS -> 2 blocks/CU.
// ---------------------------------------------------------------------------
__global__ __launch_bounds__(256, 2) void pv128(const u16* __restrict__ Hbb,
    const u16* __restrict__ H2bb, const u16* __restrict__ Sbase,
    const float* __restrict__ rsb, const float* __restrict__ content,
    const float* __restrict__ mub, const float* __restrict__ isdb,
    float* __restrict__ out, int strip_base, int bg0, size_t s_stride, int swz)
{
    const int gb = blockIdx.y;
    const size_t TBe = (size_t)CDIM * NPIX;
    const u16* Hb = Hbb + (size_t)gb * TBe;
    const u16* H2 = H2bb + (size_t)gb * TBe;
    const u16* Sb = Sbase + (size_t)gb * s_stride;
    const float* rs = rsb + (size_t)gb * NPIX;
    const float* content_b = content + (size_t)(bg0 + gb) * TBe;
    const float* mu  = mub  + (size_t)(bg0 + gb) * CDIM;
    const float* isd = isdb + (size_t)(bg0 + gb) * CDIM;
    float* out_b = out + (size_t)(bg0 + gb) * TBe;

    const int t = threadIdx.x;
    const int lane = t & 63, wv = t >> 6;       // 4 waves
    const int wr = wv >> 1, wc = wv & 1;        // 2 x 2
    const int l31 = lane & 31, h = lane >> 5;

    int c_t, n_t;
    if (swz) {          // gridDim.x % 8 == 0
        const int chunk = (int)gridDim.x >> 3;
        const int id = (blockIdx.x & 7) * chunk + (blockIdx.x >> 3);
        c_t = id & 3;                           // CDIM/128 == 4
        n_t = id >> 2;
    } else {
        c_t = blockIdx.x & 3;
        n_t = blockIdx.x >> 2;
    }
    const int c0  = c_t * 128;
    const int nl0 = n_t * 128;

    __shared__ short AS[2][128][128];           // 2 x 32 KB

    f32x16 am[2][2] = {};
    f32x16 aq[2][2] = {};

    const int lr = lane >> 4, lq = lane & 15;

    #define PV_STAGE(BUF, KB)                                                  \
    {                                                                          \
        _Pragma("unroll")                                                      \
        for (int ch = 0; ch < 8; ch++) {                                       \
            const int r0 = wv*32 + ch*4;                                       \
            const int r  = r0 + lr;                                            \
            const int c  = lq ^ (r & 15);                                      \
            const int cs = c & 3;                                              \
            const int st = c >> 2;                                             \
            const u16* gp = (st == 2)                                          \
                ? &Sb[(size_t)(nl0 + r) * NPIX + (KB) + cs*8]                  \
                : (st == 1)                                                    \
                ? &H2[(size_t)(c0  + r) * NPIX + (KB) + cs*8]                  \
                : &Hb[(size_t)(c0  + r) * NPIX + (KB) + cs*8];                 \
            GLD16(gp, &AS[BUF][r0][0]);                                        \
        }                                                                      \
    }

    PV_STAGE(0, 0);

    int buf = 0;
    for (int kb = 0; kb < NPIX; kb += 32) {
        if (kb + 32 < NPIX) {
            PV_STAGE(buf ^ 1, kb + 32);
            asm volatile("s_waitcnt vmcnt(8)" ::: "memory");   // tile t landed
        } else {
            asm volatile("s_waitcnt vmcnt(0)" ::: "memory");
        }
        __builtin_amdgcn_s_barrier();
        #pragma unroll
        for (int ks = 0; ks < 2; ks++) {
            const int sg = ks*2 + h;            // logical k-seg 0..3
            bf16x8 a[2], a2[2], b[2];
            #pragma unroll
            for (int i = 0; i < 2; i++) {
                const int q = wr*64 + i*32 + l31;          // H row
                a[i]  = *(const bf16x8*)&AS[buf][q][((    sg) ^ (q & 15)) * 8];
                a2[i] = *(const bf16x8*)&AS[buf][q][((4 + sg) ^ (q & 15)) * 8];
            }
            #pragma unroll
            for (int j = 0; j < 2; j++) {
                const int q = wc*64 + j*32 + l31;          // S row
                b[j] = *(const bf16x8*)&AS[buf][q][((8 + sg) ^ (q & 15)) * 8];
            }
            #pragma unroll
            for (int i = 0; i < 2; i++)
                #pragma unroll
                for (int j = 0; j < 2; j++) {
                    am[i][j] = MFMA32(a[i],  b[j], am[i][j], 0, 0, 0);
                    aq[i][j] = MFMA32(a2[i], b[j], aq[i][j], 0, 0, 0);
                }
        }
        __builtin_amdgcn_s_barrier();      // reads done -> next issue may reuse buf
        buf ^= 1;
    }
    #undef PV_STAGE

    // C layout (32x32): col = lane&31 (n), row = (reg&3) + 8*(reg>>2) + 4*h (c)
    #pragma unroll
    for (int j = 0; j < 2; j++) {
        const int n = strip_base + nl0 + wc*64 + j*32 + l31;
        const float inv = 1.f / (rs[n] + EPSN);
        #pragma unroll
        for (int i = 0; i < 2; i++) {
            #pragma unroll
            for (int qd = 0; qd < 4; qd++) {
                const int cb = c0 + wr*64 + i*32 + 8*qd + 4*h;
                float4 mu4 = *(const float4*)&mu[cb];
                float4 is4 = *(const float4*)&isd[cb];
                const float muA[4] = { mu4.x, mu4.y, mu4.z, mu4.w };
                const float isA[4] = { is4.x, is4.y, is4.z, is4.w };
                #pragma unroll
                for (int r2 = 0; r2 < 4; r2++) {
                    const int reg = qd*4 + r2;
                    float mean = am[i][j][reg] * inv;
                    float msq  = aq[i][j][reg] * inv;
                    float sd   = sqrtf(fmaxf(msq - mean*mean, 0.f));
                    float cv   = content_b[(size_t)(cb + r2) * NPIX + n];
                    out_b[(size_t)(cb + r2) * NPIX + n] = sd * (cv - muA[r2]) * isA[r2] + mean;
                }
            }
        }
    }
}

// ---------------------------------------------------------------------------
// content_stats: per (b,c) mean and 1/std (unbiased var, +1e-5), fp32 input
// ---------------------------------------------------------------------------
__global__ __launch_bounds__(256) void content_stats(const float* __restrict__ x,
    float* __restrict__ mu, float* __restrict__ isd)
{
    const int bc = blockIdx.x;
    const int tid = threadIdx.x;
    const float* row = x + (size_t)bc * NPIX;
    float s = 0.f, s2 = 0.f;
    for (int i = tid * 4; i < NPIX; i += 256 * 4) {
        float4 v = *(const float4*)&row[i];
        s  += v.x + v.y + v.z + v.w;
        s2 += v.x*v.x + v.y*v.y + v.z*v.z + v.w*v.w;
    }
    __shared__ float r1[256], r2[256];
    r1[tid] = s; r2[tid] = s2; __syncthreads();
    for (int st = 128; st; st >>= 1) {
        if (tid < st) { r1[tid] += r1[tid+st]; r2[tid] += r2[tid+st]; }
        __syncthreads();
    }
    if (tid == 0) {
        float m = r1[0] / NPIX;
        float var = (r2[0] - (float)NPIX * m * m) / (float)(NPIX - 1);
        mu[bc]  = m;
        isd[bc] = rsqrtf(var + 1e-5f);
    }
}

// ---------------------------------------------------------------------------
extern "C" void kernel_launch(void* const* d_in, const int* in_sizes, int n_in,
                              void* d_out, int out_size, void* d_ws, size_t ws_size,
                              hipStream_t stream)
{
    const float* content     = (const float*)d_in[0];
    const float* style       = (const float*)d_in[1];
    const float* content_key = (const float*)d_in[2];
    const float* style_key   = (const float*)d_in[3];
    const float* Wf  = (const float*)d_in[4];
    const float* bf_ = (const float*)d_in[5];
    const float* Wg  = (const float*)d_in[6];
    const float* bg  = (const float*)d_in[7];
    const float* Wh  = (const float*)d_in[8];
    const float* bh  = (const float*)d_in[9];
    float* out = (float*)d_out;

    const size_t TB = (size_t)CDIM * NPIX;   // elems per batch-tensor
    const size_t tail_bytes = (3 * (size_t)B_SZ * NPIX + 2 * (size_t)B_SZ * CDIM) * 4 + 256;

    // choose (nb, ns): bytes = nb*(6*TB + NPIX*ns)*2 + tail
    int nb = 1, ns = 512;
    {
        const int nbc[5] = {4, 2, 4, 2, 1};
        const int nsc[5] = {4096, 4096, 2048, 2048, 4096};
        bool found = false;
        for (int i = 0; i < 5; i++) {
            size_t need = (size_t)nbc[i] * (6 * TB + (size_t)NPIX * nsc[i]) * 2 + tail_bytes;
            if (need <= ws_size) { nb = nbc[i]; ns = nsc[i]; found = true; break; }
        }
        if (!found) {
            nb = 1;
            for (int cand = 2048; cand >= 512; cand >>= 1) {
                size_t need = (6 * TB + (size_t)NPIX * cand) * 2 + tail_bytes;
                if (need <= ws_size) { ns = cand; break; }
            }
        }
    }
    const size_t s_stride = (size_t)NPIX * ns;   // elems per batch S strip

    u16* FT  = (u16*)d_ws;                   // nb x [NPIX][CDIM]
    u16* GT  = FT + (size_t)nb * TB;
    u16* Hb  = GT + (size_t)nb * TB;         // nb x [CDIM][NPIX]
    u16* XT  = Hb + (size_t)nb * TB;         // nb*3 x [NPIX][CDIM]
    u16* Sb  = XT + (size_t)nb * 3 * TB;     // nb x [ns][NPIX]
    u16* H2b = XT;                           // reuse XT slab (free after conv3b)
    float* Fn  = (float*)(Sb + (size_t)nb * s_stride);
    float* Gn  = Fn + (size_t)B_SZ * NPIX;
    float* rsb = Gn + (size_t)B_SZ * NPIX;
    float* mu  = rsb + (size_t)B_SZ * NPIX;
    float* isd = mu + (size_t)B_SZ * CDIM;

    content_stats<<<B_SZ * CDIM, 256, 0, stream>>>(content, mu, isd);

    const int sg_swz = ((ns / 128) % 8 == 0) ? 1 : 0;
    const int sg_blocks = (NPIX / 128) * (ns / 128);
    const int pv_blocks = (CDIM / 128) * (ns / 128);
    const int pv_swz = (pv_blocks % 8 == 0) ? 1 : 0;

    for (int bg0 = 0; bg0 < B_SZ; bg0 += nb) {
        const int g = (bg0 + nb <= B_SZ) ? nb : (B_SZ - bg0);

        transpose3b<<<dim3(NPIX/64, CDIM/64, 3*g), 256, 0, stream>>>(
                content_key, style_key, style, XT, bg0);

        conv3b<<<dim3(NPIX/64, CDIM/64, 3*g), 256, 0, stream>>>(
                XT, Wf, Wg, Wh, bf_, bg, bh, FT, GT, Hb);

        // XT consumed; overwrite its slab with H^2 (pv stages it instead of
        // recomputing — r18's VALU bottleneck)
        {
            const size_t total8 = (size_t)g * TB / 8;
            sq_h<<<(unsigned)((total8 + 255) / 256), 256, 0, stream>>>(Hb, H2b, total8);
        }

        norm2b<<<dim3(NPIX/256, 2*g), 256, 0, stream>>>(FT, GT, Fn, Gn, rsb);

        for (int s0 = 0; s0 < NPIX; s0 += ns) {
            s_gemm128<<<dim3(sg_blocks, g), 256, 0, stream>>>(FT, GT, Fn, Gn,
                    Sb, rsb, s0, sg_swz, s_stride);
            pv128<<<dim3(pv_blocks, g), 256, 0, stream>>>(Hb, H2b, Sb, rsb,
                    content, mu, isd, out, s0, bg0, s_stride, pv_swz);
        }
    }
}

// Round 20
// 409.089 us; speedup vs baseline: 1.1488x; 1.1488x over previous
//
#include <hip/hip_runtime.h>
#include <hip/hip_bf16.h>
#include <math.h>

#define B_SZ 4
#define CDIM 512
#define NPIX 4096
#define EPSN 1e-5f

typedef unsigned short u16;
typedef __attribute__((ext_vector_type(8))) short bf16x8;
typedef __attribute__((ext_vector_type(4))) float f32x4;
typedef __attribute__((ext_vector_type(16))) float f32x16;

#define MFMA_BF16 __builtin_amdgcn_mfma_f32_16x16x32_bf16
#define MFMA32    __builtin_amdgcn_mfma_f32_32x32x16_bf16

// async global->LDS DMA, 16B per lane; LDS dest = wave-uniform base + lane*16
#define GLD16(gp, lp) __builtin_amdgcn_global_load_lds( \
    (const __attribute__((address_space(1))) void*)(gp), \
    (__attribute__((address_space(3))) void*)(lp), 16, 0, 0)

static __device__ __forceinline__ float bf2f(u16 u) {
    return __uint_as_float(((unsigned)u) << 16);
}
static __device__ __forceinline__ u16 f2bf(float f) {
    unsigned u = __float_as_uint(f);
    unsigned r = (u + 0x7FFFu + ((u >> 16) & 1u)) >> 16;
    return (u16)r;
}
// packed square of a bf16x8 fragment, truncating round; v_perm repack
static __device__ __forceinline__ bf16x8 sq_bf16x8(bf16x8 a) {
    union { bf16x8 v; unsigned w[4]; } in, out;
    in.v = a;
    #pragma unroll
    for (int k = 0; k < 4; k++) {
        unsigned wl = in.w[k] << 16;
        unsigned wh = in.w[k] & 0xFFFF0000u;
        float sl = __uint_as_float(wl); sl *= sl;
        float sh = __uint_as_float(wh); sh *= sh;
        out.w[k] = __builtin_amdgcn_perm(__float_as_uint(sh), __float_as_uint(sl),
                                         0x07060302u);
    }
    return out.v;
}

// ---------------------------------------------------------------------------
// conv_fused: z = gb*3 + which. D[o][n] = bias[o] + sum_c W[o][c]*X[c][n],
// X read DIRECTLY as fp32 [CDIM][NPIX] (transpose folded into LDS staging:
// register-staged f2bf + ushort2 transposed writes, ~2-way conflicts = free).
// which<2: store D^T to (FT|GT)+gb*TB ([n][CDIM]); which==2: Hb+gb*TB.
// Replaces the separate transpose3b kernel + XT round-trip (r19 post-mortem:
// cut launches + 8 MB/tensor of traffic with zero numerical change).
// ---------------------------------------------------------------------------
__global__ __launch_bounds__(256) void conv_fused(
    const float* __restrict__ X0, const float* __restrict__ X1, const float* __restrict__ X2,
    const float* __restrict__ W0, const float* __restrict__ W1, const float* __restrict__ W2,
    const float* __restrict__ b0, const float* __restrict__ b1, const float* __restrict__ b2,
    u16* __restrict__ FTb, u16* __restrict__ GTb, u16* __restrict__ Hbb, int bg0)
{
    const int z = blockIdx.z;
    const int gb = z / 3, which = z % 3;
    const size_t TBe = (size_t)CDIM * NPIX;
    const float* X = (which == 0 ? X0 : which == 1 ? X1 : X2) + (size_t)(bg0 + gb) * TBe;
    const float* W = which == 0 ? W0 : which == 1 ? W1 : W2;
    const float* bias = which == 0 ? b0 : which == 1 ? b1 : b2;

    const int t = threadIdx.x;
    const int lane = t & 63, wv = t >> 6;
    const int wr = wv >> 1, wc = wv & 1;
    const int n0 = blockIdx.x * 64;
    const int o0 = blockIdx.y * 64;
    const int g = lane >> 4, li = lane & 15;

    __shared__ short Aw[64][40];   // W rows (o), k=c
    __shared__ short Bx[64][40];   // X^T rows (n), k=c  (transposed on write)

    f32x4 acc[2][2] = {};
    const int srow = t >> 2, sseg = (t & 3) * 8;   // W loader
    const int cp = t & 15, ng = t >> 4;            // X loader: c-pair, n-group

    float4 w0 = *(const float4*)&W[(size_t)(o0 + srow) * CDIM + sseg];
    float4 w1 = *(const float4*)&W[(size_t)(o0 + srow) * CDIM + sseg + 4];
    float4 xa = *(const float4*)&X[(size_t)(2*cp    ) * NPIX + n0 + ng*4];
    float4 xb = *(const float4*)&X[(size_t)(2*cp + 1) * NPIX + n0 + ng*4];

    for (int kb = 0; kb < CDIM; kb += 32) {
        bf16x8 wa;
        wa[0] = (short)f2bf(w0.x); wa[1] = (short)f2bf(w0.y);
        wa[2] = (short)f2bf(w0.z); wa[3] = (short)f2bf(w0.w);
        wa[4] = (short)f2bf(w1.x); wa[5] = (short)f2bf(w1.y);
        wa[6] = (short)f2bf(w1.z); wa[7] = (short)f2bf(w1.w);
        u16 xlo[4], xhi[4];
        xlo[0] = f2bf(xa.x); xlo[1] = f2bf(xa.y); xlo[2] = f2bf(xa.z); xlo[3] = f2bf(xa.w);
        xhi[0] = f2bf(xb.x); xhi[1] = f2bf(xb.y); xhi[2] = f2bf(xb.z); xhi[3] = f2bf(xb.w);
        __syncthreads();
        *(bf16x8*)&Aw[srow][sseg] = wa;
        #pragma unroll
        for (int i = 0; i < 4; i++) {
            unsigned pk = (unsigned)xlo[i] | ((unsigned)xhi[i] << 16);
            *(unsigned*)&Bx[ng*4 + i][2*cp] = pk;
        }
        if (kb + 32 < CDIM) {
            w0 = *(const float4*)&W[(size_t)(o0 + srow) * CDIM + kb + 32 + sseg];
            w1 = *(const float4*)&W[(size_t)(o0 + srow) * CDIM + kb + 32 + sseg + 4];
            xa = *(const float4*)&X[(size_t)(kb + 32 + 2*cp    ) * NPIX + n0 + ng*4];
            xb = *(const float4*)&X[(size_t)(kb + 32 + 2*cp + 1) * NPIX + n0 + ng*4];
        }
        __syncthreads();
        bf16x8 a[2], b[2];
        #pragma unroll
        for (int i = 0; i < 2; i++) a[i] = *(const bf16x8*)&Aw[wr*32 + i*16 + li][g*8];
        #pragma unroll
        for (int j = 0; j < 2; j++) b[j] = *(const bf16x8*)&Bx[wc*32 + j*16 + li][g*8];
        #pragma unroll
        for (int i = 0; i < 2; i++)
            #pragma unroll
            for (int j = 0; j < 2; j++)
                acc[i][j] = MFMA_BF16(a[i], b[j], acc[i][j], 0, 0, 0);
    }

    #pragma unroll
    for (int i = 0; i < 2; i++) {
        const int orow = o0 + wr*32 + i*16 + 4*g;
        float4 bs = *(const float4*)&bias[orow];
        #pragma unroll
        for (int j = 0; j < 2; j++) {
            const int ncol = n0 + wc*32 + j*16 + li;
            if (which < 2) {
                u16* Y = (which == 0 ? FTb : GTb) + (size_t)gb * TBe;
                ushort4 r;
                r.x = f2bf(acc[i][j][0] + bs.x);
                r.y = f2bf(acc[i][j][1] + bs.y);
                r.z = f2bf(acc[i][j][2] + bs.z);
                r.w = f2bf(acc[i][j][3] + bs.w);
                *(ushort4*)&Y[(size_t)ncol * CDIM + orow] = r;
            } else {
                u16* Y2 = Hbb + (size_t)gb * TBe;
                const float bb[4] = { bs.x, bs.y, bs.z, bs.w };
                #pragma unroll
                for (int r = 0; r < 4; r++)
                    Y2[(size_t)(orow + r) * NPIX + ncol] = f2bf(acc[i][j][r] + bb[r]);
            }
        }
    }
}

// ---------------------------------------------------------------------------
// norm2b: blockIdx.y = gb*2 + z. z=0: Fn[gb][n], rs[gb][n]=0 ; z=1: Gn[gb][n]
// ---------------------------------------------------------------------------
__global__ __launch_bounds__(256) void norm2b(const u16* __restrict__ FT,
    const u16* __restrict__ GT, float* __restrict__ Fn, float* __restrict__ Gn,
    float* __restrict__ rs)
{
    const int gb = blockIdx.y >> 1, z = blockIdx.y & 1;
    const size_t TBe = (size_t)CDIM * NPIX;
    const int n = blockIdx.x * 256 + threadIdx.x;
    const u16* row = ((z ? GT : FT) + (size_t)gb * TBe) + (size_t)n * CDIM;
    float s = 0.f;
    for (int c = 0; c < CDIM; c += 8) {
        bf16x8 v = *(const bf16x8*)&row[c];
        #pragma unroll
        for (int e = 0; e < 8; e++) { float f = bf2f((u16)v[e]); s += f * f; }
    }
    ((z ? Gn : Fn) + (size_t)gb * NPIX)[n] = sqrtf(s);
    if (!z) rs[(size_t)gb * NPIX + n] = 0.f;
}

// ---------------------------------------------------------------------------
// s_gemm128: S[nl][m] = bf16(relu(dot/((Fn+e)(Gn+e)) + 1)), + rowsum atomics.
// 128x128 tile, 4 waves (2x2 of 64x64), K-step 32, gld_lds DMA staging with
// source-side swizzle, T4 counted-vmcnt sync. (r18, proven)
// ---------------------------------------------------------------------------
__global__ __launch_bounds__(256) void s_gemm128(const u16* __restrict__ FTb,
    const u16* __restrict__ GTb, const float* __restrict__ Fnb, const float* __restrict__ Gnb,
    u16* __restrict__ Sbase, float* __restrict__ rsb, int strip_base, int swz,
    size_t s_stride)
{
    const int gb = blockIdx.y;
    const size_t TBe = (size_t)CDIM * NPIX;
    const u16* FT = FTb + (size_t)gb * TBe;
    const u16* GT = GTb + (size_t)gb * TBe;
    const float* Fn = Fnb + (size_t)gb * NPIX;
    const float* Gn = Gnb + (size_t)gb * NPIX;
    u16* S = Sbase + (size_t)gb * s_stride;
    float* rs = rsb + (size_t)gb * NPIX;

    const int t = threadIdx.x;
    const int lane = t & 63, wv = t >> 6;
    const int wr = wv >> 1, wc = wv & 1;

    int mm, nn;
    if (swz) {            // (ns/128) % 8 == 0
        const int xk = blockIdx.x & 7, q = blockIdx.x >> 3;
        mm = q & 31;                      // NPIX/128 == 32
        nn = (q >> 5) * 8 + xk;
    } else {
        mm = blockIdx.x & 31;
        nn = blockIdx.x >> 5;
    }
    const int m0  = mm * 128;
    const int nl0 = nn * 128;
    const int ng0 = strip_base + nl0;
    const int g = lane >> 4, li = lane & 15;

    __shared__ short Cs[2][128][64];   // 32 KB total

    f32x4 acc[4][4] = {};

    const int lr = lane >> 3, lq = lane & 7;

    #define SG_STAGE(BUF, KB)                                                  \
    {                                                                          \
        _Pragma("unroll")                                                      \
        for (int ch = 0; ch < 4; ch++) {                                       \
            const int r0 = wv*32 + ch*8;                                       \
            const int r  = r0 + lr;                                            \
            const int c  = lq ^ (r & 7);                                       \
            const u16* gp = (c < 4)                                            \
                ? &FT[(size_t)(ng0 + r) * CDIM + (KB) + c*8]                   \
                : &GT[(size_t)(m0  + r) * CDIM + (KB) + (c-4)*8];              \
            GLD16(gp, &Cs[BUF][r0][0]);                                        \
        }                                                                      \
    }

    SG_STAGE(0, 0);

    int buf = 0;
    for (int kb = 0; kb < CDIM; kb += 32) {
        if (kb + 32 < CDIM) {
            SG_STAGE(buf ^ 1, kb + 32);
            asm volatile("s_waitcnt vmcnt(4)" ::: "memory");   // tile t landed
        } else {
            asm volatile("s_waitcnt vmcnt(0)" ::: "memory");
        }
        __builtin_amdgcn_s_barrier();
        bf16x8 a[4], b[4];
        #pragma unroll
        for (int i = 0; i < 4; i++) {
            const int row = wr*64 + i*16 + li;
            a[i] = *(const bf16x8*)&Cs[buf][row][(g ^ (row & 7)) * 8];
        }
        #pragma unroll
        for (int j = 0; j < 4; j++) {
            const int row = wc*64 + j*16 + li;
            b[j] = *(const bf16x8*)&Cs[buf][row][((4 + g) ^ (row & 7)) * 8];
        }
        #pragma unroll
        for (int i = 0; i < 4; i++)
            #pragma unroll
            for (int j = 0; j < 4; j++)
                acc[i][j] = MFMA_BF16(a[i], b[j], acc[i][j], 0, 0, 0);
        __builtin_amdgcn_s_barrier();      // reads done -> next issue may reuse buf
        buf ^= 1;
    }
    #undef SG_STAGE

    float gi[4];
    #pragma unroll
    for (int j = 0; j < 4; j++) gi[j] = 1.f / (Gn[m0 + wc*64 + j*16 + li] + EPSN);
    #pragma unroll
    for (int i = 0; i < 4; i++) {
        const int nl = nl0 + wr*64 + i*16 + 4*g;
        float4 fn4 = *(const float4*)&Fn[strip_base + nl];
        const float fi4[4] = { 1.f/(fn4.x + EPSN), 1.f/(fn4.y + EPSN),
                               1.f/(fn4.z + EPSN), 1.f/(fn4.w + EPSN) };
        float ps[4] = {0.f, 0.f, 0.f, 0.f};
        #pragma unroll
        for (int j = 0; j < 4; j++) {
            const int m = m0 + wc*64 + j*16 + li;
            #pragma unroll
            for (int r = 0; r < 4; r++) {
                float v = fmaxf(acc[i][j][r] * fi4[r] * gi[j] + 1.f, 0.f);
                u16 hv = f2bf(v);
                S[(size_t)(nl + r) * NPIX + m] = hv;
                ps[r] += bf2f(hv);
            }
        }
        #pragma unroll
        for (int r = 0; r < 4; r++) {
            float p = ps[r];
            p += __shfl_xor(p, 1);
            p += __shfl_xor(p, 2);
            p += __shfl_xor(p, 4);
            p += __shfl_xor(p, 8);
            if (li == 0) atomicAdd(&rs[strip_base + nl + r], p);
        }
    }
}

// ---------------------------------------------------------------------------
// pv128 (r18, proven 143.7 us): mean/msq via MFMA 32x32x16, H^2 in-register.
// Tile 128c x 128n, 4 waves of 64x64. K-step 64, counted vmcnt(8), raw
// barriers, 16-slot XOR involution LDS (2x32KB), 2 blocks/CU.
// ---------------------------------------------------------------------------
__global__ __launch_bounds__(256, 2) void pv128(const u16* __restrict__ Hbb,
    const u16* __restrict__ Sbase, const float* __restrict__ rsb,
    const float* __restrict__ content, const float* __restrict__ mub,
    const float* __restrict__ isdb, float* __restrict__ out, int strip_base,
    int bg0, size_t s_stride, int swz)
{
    const int gb = blockIdx.y;
    const size_t TBe = (size_t)CDIM * NPIX;
    const u16* Hb = Hbb + (size_t)gb * TBe;
    const u16* Sb = Sbase + (size_t)gb * s_stride;
    const float* rs = rsb + (size_t)gb * NPIX;
    const float* content_b = content + (size_t)(bg0 + gb) * TBe;
    const float* mu  = mub  + (size_t)(bg0 + gb) * CDIM;
    const float* isd = isdb + (size_t)(bg0 + gb) * CDIM;
    float* out_b = out + (size_t)(bg0 + gb) * TBe;

    const int t = threadIdx.x;
    const int lane = t & 63, wv = t >> 6;       // 4 waves
    const int wr = wv >> 1, wc = wv & 1;        // 2 x 2
    const int l31 = lane & 31, h = lane >> 5;

    int c_t, n_t;
    if (swz) {          // gridDim.x % 8 == 0
        const int chunk = (int)gridDim.x >> 3;
        const int id = (blockIdx.x & 7) * chunk + (blockIdx.x >> 3);
        c_t = id & 3;                           // CDIM/128 == 4
        n_t = id >> 2;
    } else {
        c_t = blockIdx.x & 3;
        n_t = blockIdx.x >> 2;
    }
    const int c0  = c_t * 128;
    const int nl0 = n_t * 128;

    __shared__ short AS[2][128][128];           // 2 x 32 KB

    f32x16 am[2][2] = {};
    f32x16 aq[2][2] = {};

    const int lr = lane >> 4, lq = lane & 15;

    #define PV_STAGE(BUF, KB)                                                  \
    {                                                                          \
        _Pragma("unroll")                                                      \
        for (int ch = 0; ch < 8; ch++) {                                       \
            const int r0 = wv*32 + ch*4;                                       \
            const int r  = r0 + lr;                                            \
            const int c  = lq ^ (r & 15);                                      \
            const u16* gp = (c < 8)                                            \
                ? &Hb[(size_t)(c0  + r) * NPIX + (KB) + c*8]                   \
                : &Sb[(size_t)(nl0 + r) * NPIX + (KB) + (c-8)*8];              \
            GLD16(gp, &AS[BUF][r0][0]);                                        \
        }                                                                      \
    }

    PV_STAGE(0, 0);

    int buf = 0;
    for (int kb = 0; kb < NPIX; kb += 64) {
        if (kb + 64 < NPIX) {
            PV_STAGE(buf ^ 1, kb + 64);
            asm volatile("s_waitcnt vmcnt(8)" ::: "memory");   // tile t landed
        } else {
            asm volatile("s_waitcnt vmcnt(0)" ::: "memory");
        }
        __builtin_amdgcn_s_barrier();
        #pragma unroll
        for (int ks = 0; ks < 4; ks++) {
            const int sg = ks*2 + h;            // logical k-seg 0..7
            bf16x8 a[2], a2[2], b[2];
            #pragma unroll
            for (int i = 0; i < 2; i++) {
                const int q = wr*64 + i*32 + l31;          // H row
                a[i]  = *(const bf16x8*)&AS[buf][q][(sg ^ (q & 15)) * 8];
                a2[i] = sq_bf16x8(a[i]);
            }
            #pragma unroll
            for (int j = 0; j < 2; j++) {
                const int q = wc*64 + j*32 + l31;          // S row
                b[j] = *(const bf16x8*)&AS[buf][q][((8 + sg) ^ (q & 15)) * 8];
            }
            #pragma unroll
            for (int i = 0; i < 2; i++)
                #pragma unroll
                for (int j = 0; j < 2; j++) {
                    am[i][j] = MFMA32(a[i],  b[j], am[i][j], 0, 0, 0);
                    aq[i][j] = MFMA32(a2[i], b[j], aq[i][j], 0, 0, 0);
                }
        }
        __builtin_amdgcn_s_barrier();      // reads done -> next issue may reuse buf
        buf ^= 1;
    }
    #undef PV_STAGE

    // C layout (32x32): col = lane&31 (n), row = (reg&3) + 8*(reg>>2) + 4*h (c)
    #pragma unroll
    for (int j = 0; j < 2; j++) {
        const int n = strip_base + nl0 + wc*64 + j*32 + l31;
        const float inv = 1.f / (rs[n] + EPSN);
        #pragma unroll
        for (int i = 0; i < 2; i++) {
            #pragma unroll
            for (int qd = 0; qd < 4; qd++) {
                const int cb = c0 + wr*64 + i*32 + 8*qd + 4*h;
                float4 mu4 = *(const float4*)&mu[cb];
                float4 is4 = *(const float4*)&isd[cb];
                const float muA[4] = { mu4.x, mu4.y, mu4.z, mu4.w };
                const float isA[4] = { is4.x, is4.y, is4.z, is4.w };
                #pragma unroll
                for (int r2 = 0; r2 < 4; r2++) {
                    const int reg = qd*4 + r2;
                    float mean = am[i][j][reg] * inv;
                    float msq  = aq[i][j][reg] * inv;
                    float sd   = sqrtf(fmaxf(msq - mean*mean, 0.f));
                    float cv   = content_b[(size_t)(cb + r2) * NPIX + n];
                    out_b[(size_t)(cb + r2) * NPIX + n] = sd * (cv - muA[r2]) * isA[r2] + mean;
                }
            }
        }
    }
}

// ---------------------------------------------------------------------------
// content_stats: per (b,c) mean and 1/std (unbiased var, +1e-5), fp32 input
// ---------------------------------------------------------------------------
__global__ __launch_bounds__(256) void content_stats(const float* __restrict__ x,
    float* __restrict__ mu, float* __restrict__ isd)
{
    const int bc = blockIdx.x;
    const int tid = threadIdx.x;
    const float* row = x + (size_t)bc * NPIX;
    float s = 0.f, s2 = 0.f;
    for (int i = tid * 4; i < NPIX; i += 256 * 4) {
        float4 v = *(const float4*)&row[i];
        s  += v.x + v.y + v.z + v.w;
        s2 += v.x*v.x + v.y*v.y + v.z*v.z + v.w*v.w;
    }
    __shared__ float r1[256], r2[256];
    r1[tid] = s; r2[tid] = s2; __syncthreads();
    for (int st = 128; st; st >>= 1) {
        if (tid < st) { r1[tid] += r1[tid+st]; r2[tid] += r2[tid+st]; }
        __syncthreads();
    }
    if (tid == 0) {
        float m = r1[0] / NPIX;
        float var = (r2[0] - (float)NPIX * m * m) / (float)(NPIX - 1);
        mu[bc]  = m;
        isd[bc] = rsqrtf(var + 1e-5f);
    }
}

// ---------------------------------------------------------------------------
extern "C" void kernel_launch(void* const* d_in, const int* in_sizes, int n_in,
                              void* d_out, int out_size, void* d_ws, size_t ws_size,
                              hipStream_t stream)
{
    const float* content     = (const float*)d_in[0];
    const float* style       = (const float*)d_in[1];
    const float* content_key = (const float*)d_in[2];
    const float* style_key   = (const float*)d_in[3];
    const float* Wf  = (const float*)d_in[4];
    const float* bf_ = (const float*)d_in[5];
    const float* Wg  = (const float*)d_in[6];
    const float* bg  = (const float*)d_in[7];
    const float* Wh  = (const float*)d_in[8];
    const float* bh  = (const float*)d_in[9];
    float* out = (float*)d_out;

    const size_t TB = (size_t)CDIM * NPIX;   // elems per batch-tensor
    const size_t tail_bytes = (3 * (size_t)B_SZ * NPIX + 2 * (size_t)B_SZ * CDIM) * 4 + 256;

    // choose (nb, ns): bytes = nb*(3*TB + NPIX*ns)*2 + tail  (no XT slab now)
    int nb = 1, ns = 512;
    {
        const int nbc[5] = {4, 2, 4, 2, 1};
        const int nsc[5] = {4096, 4096, 2048, 2048, 4096};
        bool found = false;
        for (int i = 0; i < 5; i++) {
            size_t need = (size_t)nbc[i] * (3 * TB + (size_t)NPIX * nsc[i]) * 2 + tail_bytes;
            if (need <= ws_size) { nb = nbc[i]; ns = nsc[i]; found = true; break; }
        }
        if (!found) {
            nb = 1;
            for (int cand = 2048; cand >= 512; cand >>= 1) {
                size_t need = (3 * TB + (size_t)NPIX * cand) * 2 + tail_bytes;
                if (need <= ws_size) { ns = cand; break; }
            }
        }
    }
    const size_t s_stride = (size_t)NPIX * ns;   // elems per batch S strip

    u16* FT  = (u16*)d_ws;                   // nb x [NPIX][CDIM]
    u16* GT  = FT + (size_t)nb * TB;
    u16* Hb  = GT + (size_t)nb * TB;         // nb x [CDIM][NPIX]
    u16* Sb  = Hb + (size_t)nb * TB;         // nb x [ns][NPIX]
    float* Fn  = (float*)(Sb + (size_t)nb * s_stride);
    float* Gn  = Fn + (size_t)B_SZ * NPIX;
    float* rsb = Gn + (size_t)B_SZ * NPIX;
    float* mu  = rsb + (size_t)B_SZ * NPIX;
    float* isd = mu + (size_t)B_SZ * CDIM;

    content_stats<<<B_SZ * CDIM, 256, 0, stream>>>(content, mu, isd);

    const int sg_swz = ((ns / 128) % 8 == 0) ? 1 : 0;
    const int sg_blocks = (NPIX / 128) * (ns / 128);
    const int pv_blocks = (CDIM / 128) * (ns / 128);
    const int pv_swz = (pv_blocks % 8 == 0) ? 1 : 0;

    for (int bg0 = 0; bg0 < B_SZ; bg0 += nb) {
        const int g = (bg0 + nb <= B_SZ) ? nb : (B_SZ - bg0);

        conv_fused<<<dim3(NPIX/64, CDIM/64, 3*g), 256, 0, stream>>>(
                content_key, style_key, style, Wf, Wg, Wh, bf_, bg, bh,
                FT, GT, Hb, bg0);

        norm2b<<<dim3(NPIX/256, 2*g), 256, 0, stream>>>(FT, GT, Fn, Gn, rsb);

        for (int s0 = 0; s0 < NPIX; s0 += ns) {
            s_gemm128<<<dim3(sg_blocks, g), 256, 0, stream>>>(FT, GT, Fn, Gn,
                    Sb, rsb, s0, sg_swz, s_stride);
            pv128<<<dim3(pv_blocks, g), 256, 0, stream>>>(Hb, Sb, rsb,
                    content, mu, isd, out, s0, bg0, s_stride, pv_swz);
        }
    }
}

// Round 21
// 380.943 us; speedup vs baseline: 1.2336x; 1.0739x over previous
//
#include <hip/hip_runtime.h>
#include <hip/hip_bf16.h>
#include <math.h>

#define B_SZ 4
#define CDIM 512
#define NPIX 4096
#define EPSN 1e-5f

typedef unsigned short u16;
typedef __attribute__((ext_vector_type(8))) short bf16x8;
typedef __attribute__((ext_vector_type(4))) float f32x4;
typedef __attribute__((ext_vector_type(16))) float f32x16;

#define MFMA_BF16 __builtin_amdgcn_mfma_f32_16x16x32_bf16
#define MFMA32    __builtin_amdgcn_mfma_f32_32x32x16_bf16

// async global->LDS DMA, 16B per lane; LDS dest = wave-uniform base + lane*16
#define GLD16(gp, lp) __builtin_amdgcn_global_load_lds( \
    (const __attribute__((address_space(1))) void*)(gp), \
    (__attribute__((address_space(3))) void*)(lp), 16, 0, 0)

static __device__ __forceinline__ float bf2f(u16 u) {
    return __uint_as_float(((unsigned)u) << 16);
}
static __device__ __forceinline__ u16 f2bf(float f) {
    unsigned u = __float_as_uint(f);
    unsigned r = (u + 0x7FFFu + ((u >> 16) & 1u)) >> 16;
    return (u16)r;
}
// packed square of a bf16x8 fragment, truncating round; v_perm repack
static __device__ __forceinline__ bf16x8 sq_bf16x8(bf16x8 a) {
    union { bf16x8 v; unsigned w[4]; } in, out;
    in.v = a;
    #pragma unroll
    for (int k = 0; k < 4; k++) {
        unsigned wl = in.w[k] << 16;
        unsigned wh = in.w[k] & 0xFFFF0000u;
        float sl = __uint_as_float(wl); sl *= sl;
        float sh = __uint_as_float(wh); sh *= sh;
        out.w[k] = __builtin_amdgcn_perm(__float_as_uint(sh), __float_as_uint(sl),
                                         0x07060302u);
    }
    return out.v;
}

// ---------------------------------------------------------------------------
// transpose3b: z = gb*3 + which; source fp32 [CDIM][NPIX] (global batch
// bg0+gb) -> XT slab entry z, bf16 [NPIX][CDIM].  (r18, proven)
// ---------------------------------------------------------------------------
__global__ __launch_bounds__(256) void transpose3b(const float* __restrict__ X0,
    const float* __restrict__ X1, const float* __restrict__ X2,
    u16* __restrict__ XTbase, int bg0)
{
    const int z = blockIdx.z;
    const int gb = z / 3, which = z % 3;
    const size_t TBe = (size_t)CDIM * NPIX;
    const float* X = (which == 0 ? X0 : which == 1 ? X1 : X2) + (size_t)(bg0 + gb) * TBe;
    u16* XT = XTbase + (size_t)z * TBe;

    __shared__ float T[64][65];
    const int t = threadIdx.x;
    const int n0 = blockIdx.x * 64, c0 = blockIdx.y * 64;
    #pragma unroll
    for (int p = 0; p < 4; p++) {
        int c_l = (t >> 4) + p * 16;
        int n_l = (t & 15) * 4;
        float4 v = *(const float4*)&X[(size_t)(c0 + c_l) * NPIX + n0 + n_l];
        T[c_l][n_l+0] = v.x; T[c_l][n_l+1] = v.y; T[c_l][n_l+2] = v.z; T[c_l][n_l+3] = v.w;
    }
    __syncthreads();
    #pragma unroll
    for (int p = 0; p < 4; p++) {
        int n_l = t >> 2;
        int cs  = (t & 3) * 4 + p * 16;
        ushort4 r;
        r.x = f2bf(T[cs+0][n_l]); r.y = f2bf(T[cs+1][n_l]);
        r.z = f2bf(T[cs+2][n_l]); r.w = f2bf(T[cs+3][n_l]);
        *(ushort4*)&XT[(size_t)(n0 + n_l) * CDIM + c0 + cs] = r;
    }
}

// ---------------------------------------------------------------------------
// conv3b: z = gb*3 + which. D[o][n] = bias[o] + sum_c W[o][c]*XT[n][c].
// which<2: store D^T to (FT|GT)+gb*TB ([n][CDIM]); which==2: Hb+gb*TB. (r18)
// ---------------------------------------------------------------------------
__global__ __launch_bounds__(256) void conv3b(const u16* __restrict__ XTbase,
    const float* __restrict__ W0, const float* __restrict__ W1, const float* __restrict__ W2,
    const float* __restrict__ b0, const float* __restrict__ b1, const float* __restrict__ b2,
    u16* __restrict__ FTb, u16* __restrict__ GTb, u16* __restrict__ Hbb)
{
    const int z = blockIdx.z;
    const int gb = z / 3, which = z % 3;
    const size_t TBe = (size_t)CDIM * NPIX;
    const u16* XT = XTbase + (size_t)z * TBe;
    const float* W = which == 0 ? W0 : which == 1 ? W1 : W2;
    const float* bias = which == 0 ? b0 : which == 1 ? b1 : b2;

    const int t = threadIdx.x;
    const int lane = t & 63, wv = t >> 6;
    const int wr = wv >> 1, wc = wv & 1;
    const int n0 = blockIdx.x * 64;
    const int o0 = blockIdx.y * 64;
    const int g = lane >> 4, li = lane & 15;

    __shared__ short Aw[64][40];
    __shared__ short Bx[64][40];

    f32x4 acc[2][2] = {};
    const int srow = t >> 2, sseg = (t & 3) * 8;

    float4 w0 = *(const float4*)&W[(size_t)(o0 + srow) * CDIM + sseg];
    float4 w1 = *(const float4*)&W[(size_t)(o0 + srow) * CDIM + sseg + 4];
    bf16x8 bv = *(const bf16x8*)&XT[(size_t)(n0 + srow) * CDIM + sseg];

    for (int kb = 0; kb < CDIM; kb += 32) {
        bf16x8 wa;
        wa[0] = (short)f2bf(w0.x); wa[1] = (short)f2bf(w0.y);
        wa[2] = (short)f2bf(w0.z); wa[3] = (short)f2bf(w0.w);
        wa[4] = (short)f2bf(w1.x); wa[5] = (short)f2bf(w1.y);
        wa[6] = (short)f2bf(w1.z); wa[7] = (short)f2bf(w1.w);
        __syncthreads();
        *(bf16x8*)&Aw[srow][sseg] = wa;
        *(bf16x8*)&Bx[srow][sseg] = bv;
        if (kb + 32 < CDIM) {
            w0 = *(const float4*)&W[(size_t)(o0 + srow) * CDIM + kb + 32 + sseg];
            w1 = *(const float4*)&W[(size_t)(o0 + srow) * CDIM + kb + 32 + sseg + 4];
            bv = *(const bf16x8*)&XT[(size_t)(n0 + srow) * CDIM + kb + 32 + sseg];
        }
        __syncthreads();
        bf16x8 a[2], b[2];
        #pragma unroll
        for (int i = 0; i < 2; i++) a[i] = *(const bf16x8*)&Aw[wr*32 + i*16 + li][g*8];
        #pragma unroll
        for (int j = 0; j < 2; j++) b[j] = *(const bf16x8*)&Bx[wc*32 + j*16 + li][g*8];
        #pragma unroll
        for (int i = 0; i < 2; i++)
            #pragma unroll
            for (int j = 0; j < 2; j++)
                acc[i][j] = MFMA_BF16(a[i], b[j], acc[i][j], 0, 0, 0);
    }

    #pragma unroll
    for (int i = 0; i < 2; i++) {
        const int orow = o0 + wr*32 + i*16 + 4*g;
        float4 bs = *(const float4*)&bias[orow];
        #pragma unroll
        for (int j = 0; j < 2; j++) {
            const int ncol = n0 + wc*32 + j*16 + li;
            if (which < 2) {
                u16* Y = (which == 0 ? FTb : GTb) + (size_t)gb * TBe;
                ushort4 r;
                r.x = f2bf(acc[i][j][0] + bs.x);
                r.y = f2bf(acc[i][j][1] + bs.y);
                r.z = f2bf(acc[i][j][2] + bs.z);
                r.w = f2bf(acc[i][j][3] + bs.w);
                *(ushort4*)&Y[(size_t)ncol * CDIM + orow] = r;
            } else {
                u16* Y2 = Hbb + (size_t)gb * TBe;
                const float bb[4] = { bs.x, bs.y, bs.z, bs.w };
                #pragma unroll
                for (int r = 0; r < 4; r++)
                    Y2[(size_t)(orow + r) * NPIX + ncol] = f2bf(acc[i][j][r] + bb[r]);
            }
        }
    }
}

// ---------------------------------------------------------------------------
// norm2b: blockIdx.y = gb*2 + z. z=0: Fn[gb][n], rs[gb][n]=0 ; z=1: Gn[gb][n]
// ---------------------------------------------------------------------------
__global__ __launch_bounds__(256) void norm2b(const u16* __restrict__ FT,
    const u16* __restrict__ GT, float* __restrict__ Fn, float* __restrict__ Gn,
    float* __restrict__ rs)
{
    const int gb = blockIdx.y >> 1, z = blockIdx.y & 1;
    const size_t TBe = (size_t)CDIM * NPIX;
    const int n = blockIdx.x * 256 + threadIdx.x;
    const u16* row = ((z ? GT : FT) + (size_t)gb * TBe) + (size_t)n * CDIM;
    float s = 0.f;
    for (int c = 0; c < CDIM; c += 8) {
        bf16x8 v = *(const bf16x8*)&row[c];
        #pragma unroll
        for (int e = 0; e < 8; e++) { float f = bf2f((u16)v[e]); s += f * f; }
    }
    ((z ? Gn : Fn) + (size_t)gb * NPIX)[n] = sqrtf(s);
    if (!z) rs[(size_t)gb * NPIX + n] = 0.f;
}

// ---------------------------------------------------------------------------
// s_gemm128: S[nl][m] = bf16(relu(dot/((Fn+e)(Gn+e)) + 1)), + rowsum atomics.
// 128x128 tile, 4 waves (2x2 of 64x64). K-STEP 64 (was 32): 32 MFMA/phase,
// 8 phases (was 16) — s_gemm ran at 530 TF vs pv's 950 with identical sync,
// the differrence was MFMA density per barrier. Staging is pv128's PROVEN
// 16-slot XOR involution, F/G instead of H/S: 256B row r = [F(ng0+r) segs
// 0-7 | G(m0+r) segs 8-15], phys slot = logical ^ (r&15), swizzle in the
// per-lane DMA source. Counted vmcnt(8), raw barriers, 64KB LDS, 2 blk/CU.
// ---------------------------------------------------------------------------
__global__ __launch_bounds__(256, 2) void s_gemm128(const u16* __restrict__ FTb,
    const u16* __restrict__ GTb, const float* __restrict__ Fnb, const float* __restrict__ Gnb,
    u16* __restrict__ Sbase, float* __restrict__ rsb, int strip_base, int swz,
    size_t s_stride)
{
    const int gb = blockIdx.y;
    const size_t TBe = (size_t)CDIM * NPIX;
    const u16* FT = FTb + (size_t)gb * TBe;
    const u16* GT = GTb + (size_t)gb * TBe;
    const float* Fn = Fnb + (size_t)gb * NPIX;
    const float* Gn = Gnb + (size_t)gb * NPIX;
    u16* S = Sbase + (size_t)gb * s_stride;
    float* rs = rsb + (size_t)gb * NPIX;

    const int t = threadIdx.x;
    const int lane = t & 63, wv = t >> 6;
    const int wr = wv >> 1, wc = wv & 1;

    int mm, nn;
    if (swz) {            // (ns/128) % 8 == 0
        const int xk = blockIdx.x & 7, q = blockIdx.x >> 3;
        mm = q & 31;                      // NPIX/128 == 32
        nn = (q >> 5) * 8 + xk;
    } else {
        mm = blockIdx.x & 31;
        nn = blockIdx.x >> 5;
    }
    const int m0  = mm * 128;
    const int nl0 = nn * 128;
    const int ng0 = strip_base + nl0;
    const int g = lane >> 4, li = lane & 15;

    __shared__ short Cs[2][128][128];   // 2 x 32 KB

    f32x4 acc[4][4] = {};

    const int lr = lane >> 4, lq = lane & 15;

    #define SG_STAGE(BUF, KB)                                                  \
    {                                                                          \
        _Pragma("unroll")                                                      \
        for (int ch = 0; ch < 8; ch++) {                                       \
            const int r0 = wv*32 + ch*4;                                       \
            const int r  = r0 + lr;                                            \
            const int c  = lq ^ (r & 15);                                      \
            const u16* gp = (c < 8)                                            \
                ? &FT[(size_t)(ng0 + r) * CDIM + (KB) + c*8]                   \
                : &GT[(size_t)(m0  + r) * CDIM + (KB) + (c-8)*8];              \
            GLD16(gp, &Cs[BUF][r0][0]);                                        \
        }                                                                      \
    }

    SG_STAGE(0, 0);

    int buf = 0;
    for (int kb = 0; kb < CDIM; kb += 64) {
        if (kb + 64 < CDIM) {
            SG_STAGE(buf ^ 1, kb + 64);
            asm volatile("s_waitcnt vmcnt(8)" ::: "memory");   // tile t landed
        } else {
            asm volatile("s_waitcnt vmcnt(0)" ::: "memory");
        }
        __builtin_amdgcn_s_barrier();
        #pragma unroll
        for (int kk = 0; kk < 2; kk++) {
            bf16x8 a[4], b[4];
            #pragma unroll
            for (int i = 0; i < 4; i++) {
                const int row = wr*64 + i*16 + li;
                a[i] = *(const bf16x8*)&Cs[buf][row][((kk*4 + g) ^ (row & 15)) * 8];
            }
            #pragma unroll
            for (int j = 0; j < 4; j++) {
                const int row = wc*64 + j*16 + li;
                b[j] = *(const bf16x8*)&Cs[buf][row][((8 + kk*4 + g) ^ (row & 15)) * 8];
            }
            #pragma unroll
            for (int i = 0; i < 4; i++)
                #pragma unroll
                for (int j = 0; j < 4; j++)
                    acc[i][j] = MFMA_BF16(a[i], b[j], acc[i][j], 0, 0, 0);
        }
        __builtin_amdgcn_s_barrier();      // reads done -> next issue may reuse buf
        buf ^= 1;
    }
    #undef SG_STAGE

    float gi[4];
    #pragma unroll
    for (int j = 0; j < 4; j++) gi[j] = 1.f / (Gn[m0 + wc*64 + j*16 + li] + EPSN);
    #pragma unroll
    for (int i = 0; i < 4; i++) {
        const int nl = nl0 + wr*64 + i*16 + 4*g;
        float4 fn4 = *(const float4*)&Fn[strip_base + nl];
        const float fi4[4] = { 1.f/(fn4.x + EPSN), 1.f/(fn4.y + EPSN),
                               1.f/(fn4.z + EPSN), 1.f/(fn4.w + EPSN) };
        float ps[4] = {0.f, 0.f, 0.f, 0.f};
        #pragma unroll
        for (int j = 0; j < 4; j++) {
            const int m = m0 + wc*64 + j*16 + li;
            #pragma unroll
            for (int r = 0; r < 4; r++) {
                float v = fmaxf(acc[i][j][r] * fi4[r] * gi[j] + 1.f, 0.f);
                u16 hv = f2bf(v);
                S[(size_t)(nl + r) * NPIX + m] = hv;
                ps[r] += bf2f(hv);
            }
        }
        #pragma unroll
        for (int r = 0; r < 4; r++) {
            float p = ps[r];
            p += __shfl_xor(p, 1);
            p += __shfl_xor(p, 2);
            p += __shfl_xor(p, 4);
            p += __shfl_xor(p, 8);
            if (li == 0) atomicAdd(&rs[strip_base + nl + r], p);
        }
    }
}

// ---------------------------------------------------------------------------
// pv128 (r18, proven 143.7 us): mean/msq via MFMA 32x32x16, H^2 in-register.
// Tile 128c x 128n, 4 waves of 64x64. K-step 64, counted vmcnt(8), raw
// barriers, 16-slot XOR involution LDS (2x32KB), 2 blocks/CU.
// ---------------------------------------------------------------------------
__global__ __launch_bounds__(256, 2) void pv128(const u16* __restrict__ Hbb,
    const u16* __restrict__ Sbase, const float* __restrict__ rsb,
    const float* __restrict__ content, const float* __restrict__ mub,
    const float* __restrict__ isdb, float* __restrict__ out, int strip_base,
    int bg0, size_t s_stride, int swz)
{
    const int gb = blockIdx.y;
    const size_t TBe = (size_t)CDIM * NPIX;
    const u16* Hb = Hbb + (size_t)gb * TBe;
    const u16* Sb = Sbase + (size_t)gb * s_stride;
    const float* rs = rsb + (size_t)gb * NPIX;
    const float* content_b = content + (size_t)(bg0 + gb) * TBe;
    const float* mu  = mub  + (size_t)(bg0 + gb) * CDIM;
    const float* isd = isdb + (size_t)(bg0 + gb) * CDIM;
    float* out_b = out + (size_t)(bg0 + gb) * TBe;

    const int t = threadIdx.x;
    const int lane = t & 63, wv = t >> 6;       // 4 waves
    const int wr = wv >> 1, wc = wv & 1;        // 2 x 2
    const int l31 = lane & 31, h = lane >> 5;

    int c_t, n_t;
    if (swz) {          // gridDim.x % 8 == 0
        const int chunk = (int)gridDim.x >> 3;
        const int id = (blockIdx.x & 7) * chunk + (blockIdx.x >> 3);
        c_t = id & 3;                           // CDIM/128 == 4
        n_t = id >> 2;
    } else {
        c_t = blockIdx.x & 3;
        n_t = blockIdx.x >> 2;
    }
    const int c0  = c_t * 128;
    const int nl0 = n_t * 128;

    __shared__ short AS[2][128][128];           // 2 x 32 KB

    f32x16 am[2][2] = {};
    f32x16 aq[2][2] = {};

    const int lr = lane >> 4, lq = lane & 15;

    #define PV_STAGE(BUF, KB)                                                  \
    {                                                                          \
        _Pragma("unroll")                                                      \
        for (int ch = 0; ch < 8; ch++) {                                       \
            const int r0 = wv*32 + ch*4;                                       \
            const int r  = r0 + lr;                                            \
            const int c  = lq ^ (r & 15);                                      \
            const u16* gp = (c < 8)                                            \
                ? &Hb[(size_t)(c0  + r) * NPIX + (KB) + c*8]                   \
                : &Sb[(size_t)(nl0 + r) * NPIX + (KB) + (c-8)*8];              \
            GLD16(gp, &AS[BUF][r0][0]);                                        \
        }                                                                      \
    }

    PV_STAGE(0, 0);

    int buf = 0;
    for (int kb = 0; kb < NPIX; kb += 64) {
        if (kb + 64 < NPIX) {
            PV_STAGE(buf ^ 1, kb + 64);
            asm volatile("s_waitcnt vmcnt(8)" ::: "memory");   // tile t landed
        } else {
            asm volatile("s_waitcnt vmcnt(0)" ::: "memory");
        }
        __builtin_amdgcn_s_barrier();
        #pragma unroll
        for (int ks = 0; ks < 4; ks++) {
            const int sg = ks*2 + h;            // logical k-seg 0..7
            bf16x8 a[2], a2[2], b[2];
            #pragma unroll
            for (int i = 0; i < 2; i++) {
                const int q = wr*64 + i*32 + l31;          // H row
                a[i]  = *(const bf16x8*)&AS[buf][q][(sg ^ (q & 15)) * 8];
                a2[i] = sq_bf16x8(a[i]);
            }
            #pragma unroll
            for (int j = 0; j < 2; j++) {
                const int q = wc*64 + j*32 + l31;          // S row
                b[j] = *(const bf16x8*)&AS[buf][q][((8 + sg) ^ (q & 15)) * 8];
            }
            #pragma unroll
            for (int i = 0; i < 2; i++)
                #pragma unroll
                for (int j = 0; j < 2; j++) {
                    am[i][j] = MFMA32(a[i],  b[j], am[i][j], 0, 0, 0);
                    aq[i][j] = MFMA32(a2[i], b[j], aq[i][j], 0, 0, 0);
                }
        }
        __builtin_amdgcn_s_barrier();      // reads done -> next issue may reuse buf
        buf ^= 1;
    }
    #undef PV_STAGE

    // C layout (32x32): col = lane&31 (n), row = (reg&3) + 8*(reg>>2) + 4*h (c)
    #pragma unroll
    for (int j = 0; j < 2; j++) {
        const int n = strip_base + nl0 + wc*64 + j*32 + l31;
        const float inv = 1.f / (rs[n] + EPSN);
        #pragma unroll
        for (int i = 0; i < 2; i++) {
            #pragma unroll
            for (int qd = 0; qd < 4; qd++) {
                const int cb = c0 + wr*64 + i*32 + 8*qd + 4*h;
                float4 mu4 = *(const float4*)&mu[cb];
                float4 is4 = *(const float4*)&isd[cb];
                const float muA[4] = { mu4.x, mu4.y, mu4.z, mu4.w };
                const float isA[4] = { is4.x, is4.y, is4.z, is4.w };
                #pragma unroll
                for (int r2 = 0; r2 < 4; r2++) {
                    const int reg = qd*4 + r2;
                    float mean = am[i][j][reg] * inv;
                    float msq  = aq[i][j][reg] * inv;
                    float sd   = sqrtf(fmaxf(msq - mean*mean, 0.f));
                    float cv   = content_b[(size_t)(cb + r2) * NPIX + n];
                    out_b[(size_t)(cb + r2) * NPIX + n] = sd * (cv - muA[r2]) * isA[r2] + mean;
                }
            }
        }
    }
}

// ---------------------------------------------------------------------------
// content_stats: per (b,c) mean and 1/std (unbiased var, +1e-5), fp32 input
// ---------------------------------------------------------------------------
__global__ __launch_bounds__(256) void content_stats(const float* __restrict__ x,
    float* __restrict__ mu, float* __restrict__ isd)
{
    const int bc = blockIdx.x;
    const int tid = threadIdx.x;
    const float* row = x + (size_t)bc * NPIX;
    float s = 0.f, s2 = 0.f;
    for (int i = tid * 4; i < NPIX; i += 256 * 4) {
        float4 v = *(const float4*)&row[i];
        s  += v.x + v.y + v.z + v.w;
        s2 += v.x*v.x + v.y*v.y + v.z*v.z + v.w*v.w;
    }
    __shared__ float r1[256], r2[256];
    r1[tid] = s; r2[tid] = s2; __syncthreads();
    for (int st = 128; st; st >>= 1) {
        if (tid < st) { r1[tid] += r1[tid+st]; r2[tid] += r2[tid+st]; }
        __syncthreads();
    }
    if (tid == 0) {
        float m = r1[0] / NPIX;
        float var = (r2[0] - (float)NPIX * m * m) / (float)(NPIX - 1);
        mu[bc]  = m;
        isd[bc] = rsqrtf(var + 1e-5f);
    }
}

// ---------------------------------------------------------------------------
extern "C" void kernel_launch(void* const* d_in, const int* in_sizes, int n_in,
                              void* d_out, int out_size, void* d_ws, size_t ws_size,
                              hipStream_t stream)
{
    const float* content     = (const float*)d_in[0];
    const float* style       = (const float*)d_in[1];
    const float* content_key = (const float*)d_in[2];
    const float* style_key   = (const float*)d_in[3];
    const float* Wf  = (const float*)d_in[4];
    const float* bf_ = (const float*)d_in[5];
    const float* Wg  = (const float*)d_in[6];
    const float* bg  = (const float*)d_in[7];
    const float* Wh  = (const float*)d_in[8];
    const float* bh  = (const float*)d_in[9];
    float* out = (float*)d_out;

    const size_t TB = (size_t)CDIM * NPIX;   // elems per batch-tensor
    const size_t tail_bytes = (3 * (size_t)B_SZ * NPIX + 2 * (size_t)B_SZ * CDIM) * 4 + 256;

    // choose (nb, ns): bytes = nb*(6*TB + NPIX*ns)*2 + tail   (XT slab back)
    int nb = 1, ns = 512;
    {
        const int nbc[5] = {4, 2, 4, 2, 1};
        const int nsc[5] = {4096, 4096, 2048, 2048, 4096};
        bool found = false;
        for (int i = 0; i < 5; i++) {
            size_t need = (size_t)nbc[i] * (6 * TB + (size_t)NPIX * nsc[i]) * 2 + tail_bytes;
            if (need <= ws_size) { nb = nbc[i]; ns = nsc[i]; found = true; break; }
        }
        if (!found) {
            nb = 1;
            for (int cand = 2048; cand >= 512; cand >>= 1) {
                size_t need = (6 * TB + (size_t)NPIX * cand) * 2 + tail_bytes;
                if (need <= ws_size) { ns = cand; break; }
            }
        }
    }
    const size_t s_stride = (size_t)NPIX * ns;   // elems per batch S strip

    u16* FT  = (u16*)d_ws;                   // nb x [NPIX][CDIM]
    u16* GT  = FT + (size_t)nb * TB;
    u16* Hb  = GT + (size_t)nb * TB;         // nb x [CDIM][NPIX]
    u16* XT  = Hb + (size_t)nb * TB;         // nb*3 x [NPIX][CDIM]
    u16* Sb  = XT + (size_t)nb * 3 * TB;     // nb x [ns][NPIX]
    float* Fn  = (float*)(Sb + (size_t)nb * s_stride);
    float* Gn  = Fn + (size_t)B_SZ * NPIX;
    float* rsb = Gn + (size_t)B_SZ * NPIX;
    float* mu  = rsb + (size_t)B_SZ * NPIX;
    float* isd = mu + (size_t)B_SZ * CDIM;

    content_stats<<<B_SZ * CDIM, 256, 0, stream>>>(content, mu, isd);

    const int sg_swz = ((ns / 128) % 8 == 0) ? 1 : 0;
    const int sg_blocks = (NPIX / 128) * (ns / 128);
    const int pv_blocks = (CDIM / 128) * (ns / 128);
    const int pv_swz = (pv_blocks % 8 == 0) ? 1 : 0;

    for (int bg0 = 0; bg0 < B_SZ; bg0 += nb) {
        const int g = (bg0 + nb <= B_SZ) ? nb : (B_SZ - bg0);

        transpose3b<<<dim3(NPIX/64, CDIM/64, 3*g), 256, 0, stream>>>(
                content_key, style_key, style, XT, bg0);

        conv3b<<<dim3(NPIX/64, CDIM/64, 3*g), 256, 0, stream>>>(
                XT, Wf, Wg, Wh, bf_, bg, bh, FT, GT, Hb);

        norm2b<<<dim3(NPIX/256, 2*g), 256, 0, stream>>>(FT, GT, Fn, Gn, rsb);

        for (int s0 = 0; s0 < NPIX; s0 += ns) {
            s_gemm128<<<dim3(sg_blocks, g), 256, 0, stream>>>(FT, GT, Fn, Gn,
                    Sb, rsb, s0, sg_swz, s_stride);
            pv128<<<dim3(pv_blocks, g), 256, 0, stream>>>(Hb, Sb, rsb,
                    content, mu, isd, out, s0, bg0, s_stride, pv_swz);
        }
    }
}

// Round 22
// 377.394 us; speedup vs baseline: 1.2452x; 1.0094x over previous
//
#include <hip/hip_runtime.h>
#include <hip/hip_bf16.h>
#include <math.h>

#define B_SZ 4
#define CDIM 512
#define NPIX 4096
#define EPSN 1e-5f

typedef unsigned short u16;
typedef __attribute__((ext_vector_type(8))) short bf16x8;
typedef __attribute__((ext_vector_type(4))) float f32x4;
typedef __attribute__((ext_vector_type(16))) float f32x16;

#define MFMA_BF16 __builtin_amdgcn_mfma_f32_16x16x32_bf16
#define MFMA32    __builtin_amdgcn_mfma_f32_32x32x16_bf16

// async global->LDS DMA, 16B per lane; LDS dest = wave-uniform base + lane*16
#define GLD16(gp, lp) __builtin_amdgcn_global_load_lds( \
    (const __attribute__((address_space(1))) void*)(gp), \
    (__attribute__((address_space(3))) void*)(lp), 16, 0, 0)

static __device__ __forceinline__ float bf2f(u16 u) {
    return __uint_as_float(((unsigned)u) << 16);
}
static __device__ __forceinline__ u16 f2bf(float f) {
    unsigned u = __float_as_uint(f);
    unsigned r = (u + 0x7FFFu + ((u >> 16) & 1u)) >> 16;
    return (u16)r;
}
// packed square of a bf16x8 fragment, truncating round; v_perm repack
static __device__ __forceinline__ bf16x8 sq_bf16x8(bf16x8 a) {
    union { bf16x8 v; unsigned w[4]; } in, out;
    in.v = a;
    #pragma unroll
    for (int k = 0; k < 4; k++) {
        unsigned wl = in.w[k] << 16;
        unsigned wh = in.w[k] & 0xFFFF0000u;
        float sl = __uint_as_float(wl); sl *= sl;
        float sh = __uint_as_float(wh); sh *= sh;
        out.w[k] = __builtin_amdgcn_perm(__float_as_uint(sh), __float_as_uint(sl),
                                         0x07060302u);
    }
    return out.v;
}

// ---------------------------------------------------------------------------
// transpose3b: z = gb*3 + which; source fp32 [CDIM][NPIX] (global batch
// bg0+gb) -> XT slab entry z, bf16 [NPIX][CDIM].  (r18, proven)
// ---------------------------------------------------------------------------
__global__ __launch_bounds__(256) void transpose3b(const float* __restrict__ X0,
    const float* __restrict__ X1, const float* __restrict__ X2,
    u16* __restrict__ XTbase, int bg0)
{
    const int z = blockIdx.z;
    const int gb = z / 3, which = z % 3;
    const size_t TBe = (size_t)CDIM * NPIX;
    const float* X = (which == 0 ? X0 : which == 1 ? X1 : X2) + (size_t)(bg0 + gb) * TBe;
    u16* XT = XTbase + (size_t)z * TBe;

    __shared__ float T[64][65];
    const int t = threadIdx.x;
    const int n0 = blockIdx.x * 64, c0 = blockIdx.y * 64;
    #pragma unroll
    for (int p = 0; p < 4; p++) {
        int c_l = (t >> 4) + p * 16;
        int n_l = (t & 15) * 4;
        float4 v = *(const float4*)&X[(size_t)(c0 + c_l) * NPIX + n0 + n_l];
        T[c_l][n_l+0] = v.x; T[c_l][n_l+1] = v.y; T[c_l][n_l+2] = v.z; T[c_l][n_l+3] = v.w;
    }
    __syncthreads();
    #pragma unroll
    for (int p = 0; p < 4; p++) {
        int n_l = t >> 2;
        int cs  = (t & 3) * 4 + p * 16;
        ushort4 r;
        r.x = f2bf(T[cs+0][n_l]); r.y = f2bf(T[cs+1][n_l]);
        r.z = f2bf(T[cs+2][n_l]); r.w = f2bf(T[cs+3][n_l]);
        *(ushort4*)&XT[(size_t)(n0 + n_l) * CDIM + c0 + cs] = r;
    }
}

// ---------------------------------------------------------------------------
// conv3b: z = gb*3 + which. D[o][n] = bias[o] + sum_c W[o][c]*XT[n][c].
// which<2: store D^T to (FT|GT)+gb*TB ([n][CDIM]); which==2: Hb+gb*TB. (r18)
// ---------------------------------------------------------------------------
__global__ __launch_bounds__(256) void conv3b(const u16* __restrict__ XTbase,
    const float* __restrict__ W0, const float* __restrict__ W1, const float* __restrict__ W2,
    const float* __restrict__ b0, const float* __restrict__ b1, const float* __restrict__ b2,
    u16* __restrict__ FTb, u16* __restrict__ GTb, u16* __restrict__ Hbb)
{
    const int z = blockIdx.z;
    const int gb = z / 3, which = z % 3;
    const size_t TBe = (size_t)CDIM * NPIX;
    const u16* XT = XTbase + (size_t)z * TBe;
    const float* W = which == 0 ? W0 : which == 1 ? W1 : W2;
    const float* bias = which == 0 ? b0 : which == 1 ? b1 : b2;

    const int t = threadIdx.x;
    const int lane = t & 63, wv = t >> 6;
    const int wr = wv >> 1, wc = wv & 1;
    const int n0 = blockIdx.x * 64;
    const int o0 = blockIdx.y * 64;
    const int g = lane >> 4, li = lane & 15;

    __shared__ short Aw[64][40];
    __shared__ short Bx[64][40];

    f32x4 acc[2][2] = {};
    const int srow = t >> 2, sseg = (t & 3) * 8;

    float4 w0 = *(const float4*)&W[(size_t)(o0 + srow) * CDIM + sseg];
    float4 w1 = *(const float4*)&W[(size_t)(o0 + srow) * CDIM + sseg + 4];
    bf16x8 bv = *(const bf16x8*)&XT[(size_t)(n0 + srow) * CDIM + sseg];

    for (int kb = 0; kb < CDIM; kb += 32) {
        bf16x8 wa;
        wa[0] = (short)f2bf(w0.x); wa[1] = (short)f2bf(w0.y);
        wa[2] = (short)f2bf(w0.z); wa[3] = (short)f2bf(w0.w);
        wa[4] = (short)f2bf(w1.x); wa[5] = (short)f2bf(w1.y);
        wa[6] = (short)f2bf(w1.z); wa[7] = (short)f2bf(w1.w);
        __syncthreads();
        *(bf16x8*)&Aw[srow][sseg] = wa;
        *(bf16x8*)&Bx[srow][sseg] = bv;
        if (kb + 32 < CDIM) {
            w0 = *(const float4*)&W[(size_t)(o0 + srow) * CDIM + kb + 32 + sseg];
            w1 = *(const float4*)&W[(size_t)(o0 + srow) * CDIM + kb + 32 + sseg + 4];
            bv = *(const bf16x8*)&XT[(size_t)(n0 + srow) * CDIM + kb + 32 + sseg];
        }
        __syncthreads();
        bf16x8 a[2], b[2];
        #pragma unroll
        for (int i = 0; i < 2; i++) a[i] = *(const bf16x8*)&Aw[wr*32 + i*16 + li][g*8];
        #pragma unroll
        for (int j = 0; j < 2; j++) b[j] = *(const bf16x8*)&Bx[wc*32 + j*16 + li][g*8];
        #pragma unroll
        for (int i = 0; i < 2; i++)
            #pragma unroll
            for (int j = 0; j < 2; j++)
                acc[i][j] = MFMA_BF16(a[i], b[j], acc[i][j], 0, 0, 0);
    }

    #pragma unroll
    for (int i = 0; i < 2; i++) {
        const int orow = o0 + wr*32 + i*16 + 4*g;
        float4 bs = *(const float4*)&bias[orow];
        #pragma unroll
        for (int j = 0; j < 2; j++) {
            const int ncol = n0 + wc*32 + j*16 + li;
            if (which < 2) {
                u16* Y = (which == 0 ? FTb : GTb) + (size_t)gb * TBe;
                ushort4 r;
                r.x = f2bf(acc[i][j][0] + bs.x);
                r.y = f2bf(acc[i][j][1] + bs.y);
                r.z = f2bf(acc[i][j][2] + bs.z);
                r.w = f2bf(acc[i][j][3] + bs.w);
                *(ushort4*)&Y[(size_t)ncol * CDIM + orow] = r;
            } else {
                u16* Y2 = Hbb + (size_t)gb * TBe;
                const float bb[4] = { bs.x, bs.y, bs.z, bs.w };
                #pragma unroll
                for (int r = 0; r < 4; r++)
                    Y2[(size_t)(orow + r) * NPIX + ncol] = f2bf(acc[i][j][r] + bb[r]);
            }
        }
    }
}

// ---------------------------------------------------------------------------
// norm2b: blockIdx.y = gb*2 + z. z=0: Fn[gb][n], rs[gb][n]=0 ; z=1: Gn[gb][n]
// ---------------------------------------------------------------------------
__global__ __launch_bounds__(256) void norm2b(const u16* __restrict__ FT,
    const u16* __restrict__ GT, float* __restrict__ Fn, float* __restrict__ Gn,
    float* __restrict__ rs)
{
    const int gb = blockIdx.y >> 1, z = blockIdx.y & 1;
    const size_t TBe = (size_t)CDIM * NPIX;
    const int n = blockIdx.x * 256 + threadIdx.x;
    const u16* row = ((z ? GT : FT) + (size_t)gb * TBe) + (size_t)n * CDIM;
    float s = 0.f;
    for (int c = 0; c < CDIM; c += 8) {
        bf16x8 v = *(const bf16x8*)&row[c];
        #pragma unroll
        for (int e = 0; e < 8; e++) { float f = bf2f((u16)v[e]); s += f * f; }
    }
    ((z ? Gn : Fn) + (size_t)gb * NPIX)[n] = sqrtf(s);
    if (!z) rs[(size_t)gb * NPIX + n] = 0.f;
}

// ---------------------------------------------------------------------------
// s_gemm128: S[nl][m] = bf16(relu(dot/((Fn+e)(Gn+e)) + 1)), + rowsum atomics.
// 128x128 tile, 4 waves (2x2 of 64x64), K-step 64, 16-slot XOR involution
// DMA staging, counted vmcnt(8). NEW: epilogue repacks the bf16 tile through
// LDS (Cs reused, padded rows [128][136]) -> 8 fully-coalesced bf16x8 store
// passes + 16-lane shfl rowsum, replacing 64 scalar short-stores + 64 shfl
// + 16 atomics (epilogue was ~15-20% of s_gemm; stores were 1/4-efficiency).
// ---------------------------------------------------------------------------
__global__ __launch_bounds__(256, 2) void s_gemm128(const u16* __restrict__ FTb,
    const u16* __restrict__ GTb, const float* __restrict__ Fnb, const float* __restrict__ Gnb,
    u16* __restrict__ Sbase, float* __restrict__ rsb, int strip_base, int swz,
    size_t s_stride)
{
    const int gb = blockIdx.y;
    const size_t TBe = (size_t)CDIM * NPIX;
    const u16* FT = FTb + (size_t)gb * TBe;
    const u16* GT = GTb + (size_t)gb * TBe;
    const float* Fn = Fnb + (size_t)gb * NPIX;
    const float* Gn = Gnb + (size_t)gb * NPIX;
    u16* S = Sbase + (size_t)gb * s_stride;
    float* rs = rsb + (size_t)gb * NPIX;

    const int t = threadIdx.x;
    const int lane = t & 63, wv = t >> 6;
    const int wr = wv >> 1, wc = wv & 1;

    int mm, nn;
    if (swz) {            // (ns/128) % 8 == 0
        const int xk = blockIdx.x & 7, q = blockIdx.x >> 3;
        mm = q & 31;                      // NPIX/128 == 32
        nn = (q >> 5) * 8 + xk;
    } else {
        mm = blockIdx.x & 31;
        nn = blockIdx.x >> 5;
    }
    const int m0  = mm * 128;
    const int nl0 = nn * 128;
    const int ng0 = strip_base + nl0;
    const int g = lane >> 4, li = lane & 15;

    __shared__ short Cs[2][128][128];   // 2 x 32 KB

    f32x4 acc[4][4] = {};

    const int lr = lane >> 4, lq = lane & 15;

    #define SG_STAGE(BUF, KB)                                                  \
    {                                                                          \
        _Pragma("unroll")                                                      \
        for (int ch = 0; ch < 8; ch++) {                                       \
            const int r0 = wv*32 + ch*4;                                       \
            const int r  = r0 + lr;                                            \
            const int c  = lq ^ (r & 15);                                      \
            const u16* gp = (c < 8)                                            \
                ? &FT[(size_t)(ng0 + r) * CDIM + (KB) + c*8]                   \
                : &GT[(size_t)(m0  + r) * CDIM + (KB) + (c-8)*8];              \
            GLD16(gp, &Cs[BUF][r0][0]);                                        \
        }                                                                      \
    }

    SG_STAGE(0, 0);

    int buf = 0;
    for (int kb = 0; kb < CDIM; kb += 64) {
        if (kb + 64 < CDIM) {
            SG_STAGE(buf ^ 1, kb + 64);
            asm volatile("s_waitcnt vmcnt(8)" ::: "memory");   // tile t landed
        } else {
            asm volatile("s_waitcnt vmcnt(0)" ::: "memory");
        }
        __builtin_amdgcn_s_barrier();
        #pragma unroll
        for (int kk = 0; kk < 2; kk++) {
            bf16x8 a[4], b[4];
            #pragma unroll
            for (int i = 0; i < 4; i++) {
                const int row = wr*64 + i*16 + li;
                a[i] = *(const bf16x8*)&Cs[buf][row][((kk*4 + g) ^ (row & 15)) * 8];
            }
            #pragma unroll
            for (int j = 0; j < 4; j++) {
                const int row = wc*64 + j*16 + li;
                b[j] = *(const bf16x8*)&Cs[buf][row][((8 + kk*4 + g) ^ (row & 15)) * 8];
            }
            #pragma unroll
            for (int i = 0; i < 4; i++)
                #pragma unroll
                for (int j = 0; j < 4; j++)
                    acc[i][j] = MFMA_BF16(a[i], b[j], acc[i][j], 0, 0, 0);
        }
        __builtin_amdgcn_s_barrier();      // reads done -> next issue may reuse buf
        buf ^= 1;
    }
    #undef SG_STAGE

    // ---- epilogue: normalize+relu -> bf16 into padded LDS tile ----
    short* Lr = &Cs[0][0][0];              // [128][136] shorts (34.8 KB < 64 KB)
    float gi[4];
    #pragma unroll
    for (int j = 0; j < 4; j++) gi[j] = 1.f / (Gn[m0 + wc*64 + j*16 + li] + EPSN);
    #pragma unroll
    for (int i = 0; i < 4; i++) {
        const int rl = wr*64 + i*16 + 4*g;
        float4 fn4 = *(const float4*)&Fn[strip_base + nl0 + rl];
        const float fi4[4] = { 1.f/(fn4.x + EPSN), 1.f/(fn4.y + EPSN),
                               1.f/(fn4.z + EPSN), 1.f/(fn4.w + EPSN) };
        #pragma unroll
        for (int j = 0; j < 4; j++) {
            const int ml = wc*64 + j*16 + li;
            #pragma unroll
            for (int r = 0; r < 4; r++) {
                float v = fmaxf(acc[i][j][r] * fi4[r] * gi[j] + 1.f, 0.f);
                Lr[(rl + r) * 136 + ml] = (short)f2bf(v);
            }
        }
    }
    __syncthreads();
    // ---- 8 coalesced passes: row rr = p*16 + (t>>4), seg = t&15 ----
    #pragma unroll
    for (int p = 0; p < 8; p++) {
        const int rr = p*16 + (t >> 4);
        bf16x8 v8 = *(const bf16x8*)&Lr[rr * 136 + li * 8];
        float ps = 0.f;
        #pragma unroll
        for (int e = 0; e < 8; e++) ps += bf2f((u16)v8[e]);
        ps += __shfl_xor(ps, 1);
        ps += __shfl_xor(ps, 2);
        ps += __shfl_xor(ps, 4);
        ps += __shfl_xor(ps, 8);
        if (li == 0) atomicAdd(&rs[strip_base + nl0 + rr], ps);
        *(bf16x8*)&S[(size_t)(nl0 + rr) * NPIX + m0 + li * 8] = v8;
    }
}

// ---------------------------------------------------------------------------
// pv128 (r18 structure, + T5 setprio around the MFMA cluster):
// mean/msq via MFMA 32x32x16, H^2 in-register. Tile 128c x 128n, 4 waves of
// 64x64, K-step 64, counted vmcnt(8), raw barriers, 16-slot XOR involution.
// ---------------------------------------------------------------------------
__global__ __launch_bounds__(256, 2) void pv128(const u16* __restrict__ Hbb,
    const u16* __restrict__ Sbase, const float* __restrict__ rsb,
    const float* __restrict__ content, const float* __restrict__ mub,
    const float* __restrict__ isdb, float* __restrict__ out, int strip_base,
    int bg0, size_t s_stride, int swz)
{
    const int gb = blockIdx.y;
    const size_t TBe = (size_t)CDIM * NPIX;
    const u16* Hb = Hbb + (size_t)gb * TBe;
    const u16* Sb = Sbase + (size_t)gb * s_stride;
    const float* rs = rsb + (size_t)gb * NPIX;
    const float* content_b = content + (size_t)(bg0 + gb) * TBe;
    const float* mu  = mub  + (size_t)(bg0 + gb) * CDIM;
    const float* isd = isdb + (size_t)(bg0 + gb) * CDIM;
    float* out_b = out + (size_t)(bg0 + gb) * TBe;

    const int t = threadIdx.x;
    const int lane = t & 63, wv = t >> 6;       // 4 waves
    const int wr = wv >> 1, wc = wv & 1;        // 2 x 2
    const int l31 = lane & 31, h = lane >> 5;

    int c_t, n_t;
    if (swz) {          // gridDim.x % 8 == 0
        const int chunk = (int)gridDim.x >> 3;
        const int id = (blockIdx.x & 7) * chunk + (blockIdx.x >> 3);
        c_t = id & 3;                           // CDIM/128 == 4
        n_t = id >> 2;
    } else {
        c_t = blockIdx.x & 3;
        n_t = blockIdx.x >> 2;
    }
    const int c0  = c_t * 128;
    const int nl0 = n_t * 128;

    __shared__ short AS[2][128][128];           // 2 x 32 KB

    f32x16 am[2][2] = {};
    f32x16 aq[2][2] = {};

    const int lr = lane >> 4, lq = lane & 15;

    #define PV_STAGE(BUF, KB)                                                  \
    {                                                                          \
        _Pragma("unroll")                                                      \
        for (int ch = 0; ch < 8; ch++) {                                       \
            const int r0 = wv*32 + ch*4;                                       \
            const int r  = r0 + lr;                                            \
            const int c  = lq ^ (r & 15);                                      \
            const u16* gp = (c < 8)                                            \
                ? &Hb[(size_t)(c0  + r) * NPIX + (KB) + c*8]                   \
                : &Sb[(size_t)(nl0 + r) * NPIX + (KB) + (c-8)*8];              \
            GLD16(gp, &AS[BUF][r0][0]);                                        \
        }                                                                      \
    }

    PV_STAGE(0, 0);

    int buf = 0;
    for (int kb = 0; kb < NPIX; kb += 64) {
        if (kb + 64 < NPIX) {
            PV_STAGE(buf ^ 1, kb + 64);
            asm volatile("s_waitcnt vmcnt(8)" ::: "memory");   // tile t landed
        } else {
            asm volatile("s_waitcnt vmcnt(0)" ::: "memory");
        }
        __builtin_amdgcn_s_barrier();
        __builtin_amdgcn_s_setprio(1);
        #pragma unroll
        for (int ks = 0; ks < 4; ks++) {
            const int sg = ks*2 + h;            // logical k-seg 0..7
            bf16x8 a[2], a2[2], b[2];
            #pragma unroll
            for (int i = 0; i < 2; i++) {
                const int q = wr*64 + i*32 + l31;          // H row
                a[i]  = *(const bf16x8*)&AS[buf][q][(sg ^ (q & 15)) * 8];
                a2[i] = sq_bf16x8(a[i]);
            }
            #pragma unroll
            for (int j = 0; j < 2; j++) {
                const int q = wc*64 + j*32 + l31;          // S row
                b[j] = *(const bf16x8*)&AS[buf][q][((8 + sg) ^ (q & 15)) * 8];
            }
            #pragma unroll
            for (int i = 0; i < 2; i++)
                #pragma unroll
                for (int j = 0; j < 2; j++) {
                    am[i][j] = MFMA32(a[i],  b[j], am[i][j], 0, 0, 0);
                    aq[i][j] = MFMA32(a2[i], b[j], aq[i][j], 0, 0, 0);
                }
        }
        __builtin_amdgcn_s_setprio(0);
        __builtin_amdgcn_s_barrier();      // reads done -> next issue may reuse buf
        buf ^= 1;
    }
    #undef PV_STAGE

    // C layout (32x32): col = lane&31 (n), row = (reg&3) + 8*(reg>>2) + 4*h (c)
    #pragma unroll
    for (int j = 0; j < 2; j++) {
        const int n = strip_base + nl0 + wc*64 + j*32 + l31;
        const float inv = 1.f / (rs[n] + EPSN);
        #pragma unroll
        for (int i = 0; i < 2; i++) {
            #pragma unroll
            for (int qd = 0; qd < 4; qd++) {
                const int cb = c0 + wr*64 + i*32 + 8*qd + 4*h;
                float4 mu4 = *(const float4*)&mu[cb];
                float4 is4 = *(const float4*)&isd[cb];
                const float muA[4] = { mu4.x, mu4.y, mu4.z, mu4.w };
                const float isA[4] = { is4.x, is4.y, is4.z, is4.w };
                #pragma unroll
                for (int r2 = 0; r2 < 4; r2++) {
                    const int reg = qd*4 + r2;
                    float mean = am[i][j][reg] * inv;
                    float msq  = aq[i][j][reg] * inv;
                    float sd   = sqrtf(fmaxf(msq - mean*mean, 0.f));
                    float cv   = content_b[(size_t)(cb + r2) * NPIX + n];
                    out_b[(size_t)(cb + r2) * NPIX + n] = sd * (cv - muA[r2]) * isA[r2] + mean;
                }
            }
        }
    }
}

// ---------------------------------------------------------------------------
// content_stats: per (b,c) mean and 1/std (unbiased var, +1e-5), fp32 input
// ---------------------------------------------------------------------------
__global__ __launch_bounds__(256) void content_stats(const float* __restrict__ x,
    float* __restrict__ mu, float* __restrict__ isd)
{
    const int bc = blockIdx.x;
    const int tid = threadIdx.x;
    const float* row = x + (size_t)bc * NPIX;
    float s = 0.f, s2 = 0.f;
    for (int i = tid * 4; i < NPIX; i += 256 * 4) {
        float4 v = *(const float4*)&row[i];
        s  += v.x + v.y + v.z + v.w;
        s2 += v.x*v.x + v.y*v.y + v.z*v.z + v.w*v.w;
    }
    __shared__ float r1[256], r2[256];
    r1[tid] = s; r2[tid] = s2; __syncthreads();
    for (int st = 128; st; st >>= 1) {
        if (tid < st) { r1[tid] += r1[tid+st]; r2[tid] += r2[tid+st]; }
        __syncthreads();
    }
    if (tid == 0) {
        float m = r1[0] / NPIX;
        float var = (r2[0] - (float)NPIX * m * m) / (float)(NPIX - 1);
        mu[bc]  = m;
        isd[bc] = rsqrtf(var + 1e-5f);
    }
}

// ---------------------------------------------------------------------------
extern "C" void kernel_launch(void* const* d_in, const int* in_sizes, int n_in,
                              void* d_out, int out_size, void* d_ws, size_t ws_size,
                              hipStream_t stream)
{
    const float* content     = (const float*)d_in[0];
    const float* style       = (const float*)d_in[1];
    const float* content_key = (const float*)d_in[2];
    const float* style_key   = (const float*)d_in[3];
    const float* Wf  = (const float*)d_in[4];
    const float* bf_ = (const float*)d_in[5];
    const float* Wg  = (const float*)d_in[6];
    const float* bg  = (const float*)d_in[7];
    const float* Wh  = (const float*)d_in[8];
    const float* bh  = (const float*)d_in[9];
    float* out = (float*)d_out;

    const size_t TB = (size_t)CDIM * NPIX;   // elems per batch-tensor
    const size_t tail_bytes = (3 * (size_t)B_SZ * NPIX + 2 * (size_t)B_SZ * CDIM) * 4 + 256;

    // choose (nb, ns): bytes = nb*(6*TB + NPIX*ns)*2 + tail
    int nb = 1, ns = 512;
    {
        const int nbc[5] = {4, 2, 4, 2, 1};
        const int nsc[5] = {4096, 4096, 2048, 2048, 4096};
        bool found = false;
        for (int i = 0; i < 5; i++) {
            size_t need = (size_t)nbc[i] * (6 * TB + (size_t)NPIX * nsc[i]) * 2 + tail_bytes;
            if (need <= ws_size) { nb = nbc[i]; ns = nsc[i]; found = true; break; }
        }
        if (!found) {
            nb = 1;
            for (int cand = 2048; cand >= 512; cand >>= 1) {
                size_t need = (6 * TB + (size_t)NPIX * cand) * 2 + tail_bytes;
                if (need <= ws_size) { ns = cand; break; }
            }
        }
    }
    const size_t s_stride = (size_t)NPIX * ns;   // elems per batch S strip

    u16* FT  = (u16*)d_ws;                   // nb x [NPIX][CDIM]
    u16* GT  = FT + (size_t)nb * TB;
    u16* Hb  = GT + (size_t)nb * TB;         // nb x [CDIM][NPIX]
    u16* XT  = Hb + (size_t)nb * TB;         // nb*3 x [NPIX][CDIM]
    u16* Sb  = XT + (size_t)nb * 3 * TB;     // nb x [ns][NPIX]
    float* Fn  = (float*)(Sb + (size_t)nb * s_stride);
    float* Gn  = Fn + (size_t)B_SZ * NPIX;
    float* rsb = Gn + (size_t)B_SZ * NPIX;
    float* mu  = rsb + (size_t)B_SZ * NPIX;
    float* isd = mu + (size_t)B_SZ * CDIM;

    content_stats<<<B_SZ * CDIM, 256, 0, stream>>>(content, mu, isd);

    const int sg_swz = ((ns / 128) % 8 == 0) ? 1 : 0;
    const int sg_blocks = (NPIX / 128) * (ns / 128);
    const int pv_blocks = (CDIM / 128) * (ns / 128);
    const int pv_swz = (pv_blocks % 8 == 0) ? 1 : 0;

    for (int bg0 = 0; bg0 < B_SZ; bg0 += nb) {
        const int g = (bg0 + nb <= B_SZ) ? nb : (B_SZ - bg0);

        transpose3b<<<dim3(NPIX/64, CDIM/64, 3*g), 256, 0, stream>>>(
                content_key, style_key, style, XT, bg0);

        conv3b<<<dim3(NPIX/64, CDIM/64, 3*g), 256, 0, stream>>>(
                XT, Wf, Wg, Wh, bf_, bg, bh, FT, GT, Hb);

        norm2b<<<dim3(NPIX/256, 2*g), 256, 0, stream>>>(FT, GT, Fn, Gn, rsb);

        for (int s0 = 0; s0 < NPIX; s0 += ns) {
            s_gemm128<<<dim3(sg_blocks, g), 256, 0, stream>>>(FT, GT, Fn, Gn,
                    Sb, rsb, s0, sg_swz, s_stride);
            pv128<<<dim3(pv_blocks, g), 256, 0, stream>>>(Hb, Sb, rsb,
                    content, mu, isd, out, s0, bg0, s_stride, pv_swz);
        }
    }
}

// Round 23
// 370.412 us; speedup vs baseline: 1.2687x; 1.0188x over previous
//
#include <hip/hip_runtime.h>
#include <hip/hip_bf16.h>
#include <math.h>

#define B_SZ 4
#define CDIM 512
#define NPIX 4096
#define EPSN 1e-5f

typedef unsigned short u16;
typedef __attribute__((ext_vector_type(8))) short bf16x8;
typedef __attribute__((ext_vector_type(4))) float f32x4;
typedef __attribute__((ext_vector_type(16))) float f32x16;

#define MFMA_BF16 __builtin_amdgcn_mfma_f32_16x16x32_bf16
#define MFMA32    __builtin_amdgcn_mfma_f32_32x32x16_bf16

// async global->LDS DMA, 16B per lane; LDS dest = wave-uniform base + lane*16
#define GLD16(gp, lp) __builtin_amdgcn_global_load_lds( \
    (const __attribute__((address_space(1))) void*)(gp), \
    (__attribute__((address_space(3))) void*)(lp), 16, 0, 0)

static __device__ __forceinline__ float bf2f(u16 u) {
    return __uint_as_float(((unsigned)u) << 16);
}
static __device__ __forceinline__ u16 f2bf(float f) {
    unsigned u = __float_as_uint(f);
    unsigned r = (u + 0x7FFFu + ((u >> 16) & 1u)) >> 16;
    return (u16)r;
}
// packed square of a bf16x8 fragment, truncating round; v_perm repack
static __device__ __forceinline__ bf16x8 sq_bf16x8(bf16x8 a) {
    union { bf16x8 v; unsigned w[4]; } in, out;
    in.v = a;
    #pragma unroll
    for (int k = 0; k < 4; k++) {
        unsigned wl = in.w[k] << 16;
        unsigned wh = in.w[k] & 0xFFFF0000u;
        float sl = __uint_as_float(wl); sl *= sl;
        float sh = __uint_as_float(wh); sh *= sh;
        out.w[k] = __builtin_amdgcn_perm(__float_as_uint(sh), __float_as_uint(sl),
                                         0x07060302u);
    }
    return out.v;
}

// ---------------------------------------------------------------------------
// transpose3b: z = gb*3 + which; source fp32 [CDIM][NPIX] (global batch
// bg0+gb) -> XT slab entry z, bf16 [NPIX][CDIM].  (r18, proven)
// ---------------------------------------------------------------------------
__global__ __launch_bounds__(256) void transpose3b(const float* __restrict__ X0,
    const float* __restrict__ X1, const float* __restrict__ X2,
    u16* __restrict__ XTbase, int bg0)
{
    const int z = blockIdx.z;
    const int gb = z / 3, which = z % 3;
    const size_t TBe = (size_t)CDIM * NPIX;
    const float* X = (which == 0 ? X0 : which == 1 ? X1 : X2) + (size_t)(bg0 + gb) * TBe;
    u16* XT = XTbase + (size_t)z * TBe;

    __shared__ float T[64][65];
    const int t = threadIdx.x;
    const int n0 = blockIdx.x * 64, c0 = blockIdx.y * 64;
    #pragma unroll
    for (int p = 0; p < 4; p++) {
        int c_l = (t >> 4) + p * 16;
        int n_l = (t & 15) * 4;
        float4 v = *(const float4*)&X[(size_t)(c0 + c_l) * NPIX + n0 + n_l];
        T[c_l][n_l+0] = v.x; T[c_l][n_l+1] = v.y; T[c_l][n_l+2] = v.z; T[c_l][n_l+3] = v.w;
    }
    __syncthreads();
    #pragma unroll
    for (int p = 0; p < 4; p++) {
        int n_l = t >> 2;
        int cs  = (t & 3) * 4 + p * 16;
        ushort4 r;
        r.x = f2bf(T[cs+0][n_l]); r.y = f2bf(T[cs+1][n_l]);
        r.z = f2bf(T[cs+2][n_l]); r.w = f2bf(T[cs+3][n_l]);
        *(ushort4*)&XT[(size_t)(n0 + n_l) * CDIM + c0 + cs] = r;
    }
}

// ---------------------------------------------------------------------------
// conv3b: z = gb*3 + which. D[o][n] = bias[o] + sum_c W[o][c]*XT[n][c].
// which<2: store D^T to (FT|GT)+gb*TB ([n][CDIM]); which==2: Hb+gb*TB. (r18)
// ---------------------------------------------------------------------------
__global__ __launch_bounds__(256) void conv3b(const u16* __restrict__ XTbase,
    const float* __restrict__ W0, const float* __restrict__ W1, const float* __restrict__ W2,
    const float* __restrict__ b0, const float* __restrict__ b1, const float* __restrict__ b2,
    u16* __restrict__ FTb, u16* __restrict__ GTb, u16* __restrict__ Hbb)
{
    const int z = blockIdx.z;
    const int gb = z / 3, which = z % 3;
    const size_t TBe = (size_t)CDIM * NPIX;
    const u16* XT = XTbase + (size_t)z * TBe;
    const float* W = which == 0 ? W0 : which == 1 ? W1 : W2;
    const float* bias = which == 0 ? b0 : which == 1 ? b1 : b2;

    const int t = threadIdx.x;
    const int lane = t & 63, wv = t >> 6;
    const int wr = wv >> 1, wc = wv & 1;
    const int n0 = blockIdx.x * 64;
    const int o0 = blockIdx.y * 64;
    const int g = lane >> 4, li = lane & 15;

    __shared__ short Aw[64][40];
    __shared__ short Bx[64][40];

    f32x4 acc[2][2] = {};
    const int srow = t >> 2, sseg = (t & 3) * 8;

    float4 w0 = *(const float4*)&W[(size_t)(o0 + srow) * CDIM + sseg];
    float4 w1 = *(const float4*)&W[(size_t)(o0 + srow) * CDIM + sseg + 4];
    bf16x8 bv = *(const bf16x8*)&XT[(size_t)(n0 + srow) * CDIM + sseg];

    for (int kb = 0; kb < CDIM; kb += 32) {
        bf16x8 wa;
        wa[0] = (short)f2bf(w0.x); wa[1] = (short)f2bf(w0.y);
        wa[2] = (short)f2bf(w0.z); wa[3] = (short)f2bf(w0.w);
        wa[4] = (short)f2bf(w1.x); wa[5] = (short)f2bf(w1.y);
        wa[6] = (short)f2bf(w1.z); wa[7] = (short)f2bf(w1.w);
        __syncthreads();
        *(bf16x8*)&Aw[srow][sseg] = wa;
        *(bf16x8*)&Bx[srow][sseg] = bv;
        if (kb + 32 < CDIM) {
            w0 = *(const float4*)&W[(size_t)(o0 + srow) * CDIM + kb + 32 + sseg];
            w1 = *(const float4*)&W[(size_t)(o0 + srow) * CDIM + kb + 32 + sseg + 4];
            bv = *(const bf16x8*)&XT[(size_t)(n0 + srow) * CDIM + kb + 32 + sseg];
        }
        __syncthreads();
        bf16x8 a[2], b[2];
        #pragma unroll
        for (int i = 0; i < 2; i++) a[i] = *(const bf16x8*)&Aw[wr*32 + i*16 + li][g*8];
        #pragma unroll
        for (int j = 0; j < 2; j++) b[j] = *(const bf16x8*)&Bx[wc*32 + j*16 + li][g*8];
        #pragma unroll
        for (int i = 0; i < 2; i++)
            #pragma unroll
            for (int j = 0; j < 2; j++)
                acc[i][j] = MFMA_BF16(a[i], b[j], acc[i][j], 0, 0, 0);
    }

    #pragma unroll
    for (int i = 0; i < 2; i++) {
        const int orow = o0 + wr*32 + i*16 + 4*g;
        float4 bs = *(const float4*)&bias[orow];
        #pragma unroll
        for (int j = 0; j < 2; j++) {
            const int ncol = n0 + wc*32 + j*16 + li;
            if (which < 2) {
                u16* Y = (which == 0 ? FTb : GTb) + (size_t)gb * TBe;
                ushort4 r;
                r.x = f2bf(acc[i][j][0] + bs.x);
                r.y = f2bf(acc[i][j][1] + bs.y);
                r.z = f2bf(acc[i][j][2] + bs.z);
                r.w = f2bf(acc[i][j][3] + bs.w);
                *(ushort4*)&Y[(size_t)ncol * CDIM + orow] = r;
            } else {
                u16* Y2 = Hbb + (size_t)gb * TBe;
                const float bb[4] = { bs.x, bs.y, bs.z, bs.w };
                #pragma unroll
                for (int r = 0; r < 4; r++)
                    Y2[(size_t)(orow + r) * NPIX + ncol] = f2bf(acc[i][j][r] + bb[r]);
            }
        }
    }
}

// ---------------------------------------------------------------------------
// norm2b: blockIdx.y = gb*2 + z. z=0: Fn[gb][n], rs[gb][n]=0 ; z=1: Gn[gb][n]
// ---------------------------------------------------------------------------
__global__ __launch_bounds__(256) void norm2b(const u16* __restrict__ FT,
    const u16* __restrict__ GT, float* __restrict__ Fn, float* __restrict__ Gn,
    float* __restrict__ rs)
{
    const int gb = blockIdx.y >> 1, z = blockIdx.y & 1;
    const size_t TBe = (size_t)CDIM * NPIX;
    const int n = blockIdx.x * 256 + threadIdx.x;
    const u16* row = ((z ? GT : FT) + (size_t)gb * TBe) + (size_t)n * CDIM;
    float s = 0.f;
    for (int c = 0; c < CDIM; c += 8) {
        bf16x8 v = *(const bf16x8*)&row[c];
        #pragma unroll
        for (int e = 0; e < 8; e++) { float f = bf2f((u16)v[e]); s += f * f; }
    }
    ((z ? Gn : Fn) + (size_t)gb * NPIX)[n] = sqrtf(s);
    if (!z) rs[(size_t)gb * NPIX + n] = 0.f;
}

// ---------------------------------------------------------------------------
// s_gemm128: S[nl][m] = bf16(relu(dot/((Fn+e)(Gn+e)) + 1)), + rowsum atomics.
// 128x128 tile, 4 waves (2x2 of 64x64), K-step 64, 16-slot XOR involution
// DMA staging, counted vmcnt(8), LDS-repacked coalesced epilogue. (r22)
// ---------------------------------------------------------------------------
__global__ __launch_bounds__(256, 2) void s_gemm128(const u16* __restrict__ FTb,
    const u16* __restrict__ GTb, const float* __restrict__ Fnb, const float* __restrict__ Gnb,
    u16* __restrict__ Sbase, float* __restrict__ rsb, int strip_base, int swz,
    size_t s_stride)
{
    const int gb = blockIdx.y;
    const size_t TBe = (size_t)CDIM * NPIX;
    const u16* FT = FTb + (size_t)gb * TBe;
    const u16* GT = GTb + (size_t)gb * TBe;
    const float* Fn = Fnb + (size_t)gb * NPIX;
    const float* Gn = Gnb + (size_t)gb * NPIX;
    u16* S = Sbase + (size_t)gb * s_stride;
    float* rs = rsb + (size_t)gb * NPIX;

    const int t = threadIdx.x;
    const int lane = t & 63, wv = t >> 6;
    const int wr = wv >> 1, wc = wv & 1;

    int mm, nn;
    if (swz) {            // (ns/128) % 8 == 0
        const int xk = blockIdx.x & 7, q = blockIdx.x >> 3;
        mm = q & 31;                      // NPIX/128 == 32
        nn = (q >> 5) * 8 + xk;
    } else {
        mm = blockIdx.x & 31;
        nn = blockIdx.x >> 5;
    }
    const int m0  = mm * 128;
    const int nl0 = nn * 128;
    const int ng0 = strip_base + nl0;
    const int g = lane >> 4, li = lane & 15;

    __shared__ short Cs[2][128][128];   // 2 x 32 KB

    f32x4 acc[4][4] = {};

    const int lr = lane >> 4, lq = lane & 15;

    #define SG_STAGE(BUF, KB)                                                  \
    {                                                                          \
        _Pragma("unroll")                                                      \
        for (int ch = 0; ch < 8; ch++) {                                       \
            const int r0 = wv*32 + ch*4;                                       \
            const int r  = r0 + lr;                                            \
            const int c  = lq ^ (r & 15);                                      \
            const u16* gp = (c < 8)                                            \
                ? &FT[(size_t)(ng0 + r) * CDIM + (KB) + c*8]                   \
                : &GT[(size_t)(m0  + r) * CDIM + (KB) + (c-8)*8];              \
            GLD16(gp, &Cs[BUF][r0][0]);                                        \
        }                                                                      \
    }

    SG_STAGE(0, 0);

    int buf = 0;
    for (int kb = 0; kb < CDIM; kb += 64) {
        if (kb + 64 < CDIM) {
            SG_STAGE(buf ^ 1, kb + 64);
            asm volatile("s_waitcnt vmcnt(8)" ::: "memory");   // tile t landed
        } else {
            asm volatile("s_waitcnt vmcnt(0)" ::: "memory");
        }
        __builtin_amdgcn_s_barrier();
        #pragma unroll
        for (int kk = 0; kk < 2; kk++) {
            bf16x8 a[4], b[4];
            #pragma unroll
            for (int i = 0; i < 4; i++) {
                const int row = wr*64 + i*16 + li;
                a[i] = *(const bf16x8*)&Cs[buf][row][((kk*4 + g) ^ (row & 15)) * 8];
            }
            #pragma unroll
            for (int j = 0; j < 4; j++) {
                const int row = wc*64 + j*16 + li;
                b[j] = *(const bf16x8*)&Cs[buf][row][((8 + kk*4 + g) ^ (row & 15)) * 8];
            }
            #pragma unroll
            for (int i = 0; i < 4; i++)
                #pragma unroll
                for (int j = 0; j < 4; j++)
                    acc[i][j] = MFMA_BF16(a[i], b[j], acc[i][j], 0, 0, 0);
        }
        __builtin_amdgcn_s_barrier();      // reads done -> next issue may reuse buf
        buf ^= 1;
    }
    #undef SG_STAGE

    // ---- epilogue: normalize+relu -> bf16 into padded LDS tile ----
    short* Lr = &Cs[0][0][0];              // [128][136] shorts (34.8 KB < 64 KB)
    float gi[4];
    #pragma unroll
    for (int j = 0; j < 4; j++) gi[j] = 1.f / (Gn[m0 + wc*64 + j*16 + li] + EPSN);
    #pragma unroll
    for (int i = 0; i < 4; i++) {
        const int rl = wr*64 + i*16 + 4*g;
        float4 fn4 = *(const float4*)&Fn[strip_base + nl0 + rl];
        const float fi4[4] = { 1.f/(fn4.x + EPSN), 1.f/(fn4.y + EPSN),
                               1.f/(fn4.z + EPSN), 1.f/(fn4.w + EPSN) };
        #pragma unroll
        for (int j = 0; j < 4; j++) {
            const int ml = wc*64 + j*16 + li;
            #pragma unroll
            for (int r = 0; r < 4; r++) {
                float v = fmaxf(acc[i][j][r] * fi4[r] * gi[j] + 1.f, 0.f);
                Lr[(rl + r) * 136 + ml] = (short)f2bf(v);
            }
        }
    }
    __syncthreads();
    #pragma unroll
    for (int p = 0; p < 8; p++) {
        const int rr = p*16 + (t >> 4);
        bf16x8 v8 = *(const bf16x8*)&Lr[rr * 136 + li * 8];
        float ps = 0.f;
        #pragma unroll
        for (int e = 0; e < 8; e++) ps += bf2f((u16)v8[e]);
        ps += __shfl_xor(ps, 1);
        ps += __shfl_xor(ps, 2);
        ps += __shfl_xor(ps, 4);
        ps += __shfl_xor(ps, 8);
        if (li == 0) atomicAdd(&rs[strip_base + nl0 + rr], ps);
        *(bf16x8*)&S[(size_t)(nl0 + rr) * NPIX + m0 + li * 8] = v8;
    }
}

// ---------------------------------------------------------------------------
// pv128: mean/msq via MFMA 32x32x16, H^2 in-register. Tile 128c x 128n,
// 4 waves of 64x64, K-step 64, counted vmcnt(8), raw barriers, 16-slot XOR
// involution LDS (2x32KB), 2 blocks/CU. NO setprio (r22: slightly negative).
// NEW epilogue: stage (sd,mean) per c-half through the freed AS buffers,
// then 8 coalesced f32x4 passes for content-read + out-write (replaces 32
// scalar 4B reads + 32 scalar 4B stores/thread = 256 MB of quarter-
// efficiency HBM traffic).
// ---------------------------------------------------------------------------
__global__ __launch_bounds__(256, 2) void pv128(const u16* __restrict__ Hbb,
    const u16* __restrict__ Sbase, const float* __restrict__ rsb,
    const float* __restrict__ content, const float* __restrict__ mub,
    const float* __restrict__ isdb, float* __restrict__ out, int strip_base,
    int bg0, size_t s_stride, int swz)
{
    const int gb = blockIdx.y;
    const size_t TBe = (size_t)CDIM * NPIX;
    const u16* Hb = Hbb + (size_t)gb * TBe;
    const u16* Sb = Sbase + (size_t)gb * s_stride;
    const float* rs = rsb + (size_t)gb * NPIX;
    const float* content_b = content + (size_t)(bg0 + gb) * TBe;
    const float* mu  = mub  + (size_t)(bg0 + gb) * CDIM;
    const float* isd = isdb + (size_t)(bg0 + gb) * CDIM;
    float* out_b = out + (size_t)(bg0 + gb) * TBe;

    const int t = threadIdx.x;
    const int lane = t & 63, wv = t >> 6;       // 4 waves
    const int wr = wv >> 1, wc = wv & 1;        // 2 x 2
    const int l31 = lane & 31, h = lane >> 5;

    int c_t, n_t;
    if (swz) {          // gridDim.x % 8 == 0
        const int chunk = (int)gridDim.x >> 3;
        const int id = (blockIdx.x & 7) * chunk + (blockIdx.x >> 3);
        c_t = id & 3;                           // CDIM/128 == 4
        n_t = id >> 2;
    } else {
        c_t = blockIdx.x & 3;
        n_t = blockIdx.x >> 2;
    }
    const int c0  = c_t * 128;
    const int nl0 = n_t * 128;

    __shared__ short AS[2][128][128];           // 2 x 32 KB

    f32x16 am[2][2] = {};
    f32x16 aq[2][2] = {};

    const int lr = lane >> 4, lq = lane & 15;

    #define PV_STAGE(BUF, KB)                                                  \
    {                                                                          \
        _Pragma("unroll")                                                      \
        for (int ch = 0; ch < 8; ch++) {                                       \
            const int r0 = wv*32 + ch*4;                                       \
            const int r  = r0 + lr;                                            \
            const int c  = lq ^ (r & 15);                                      \
            const u16* gp = (c < 8)                                            \
                ? &Hb[(size_t)(c0  + r) * NPIX + (KB) + c*8]                   \
                : &Sb[(size_t)(nl0 + r) * NPIX + (KB) + (c-8)*8];              \
            GLD16(gp, &AS[BUF][r0][0]);                                        \
        }                                                                      \
    }

    PV_STAGE(0, 0);

    int buf = 0;
    for (int kb = 0; kb < NPIX; kb += 64) {
        if (kb + 64 < NPIX) {
            PV_STAGE(buf ^ 1, kb + 64);
            asm volatile("s_waitcnt vmcnt(8)" ::: "memory");   // tile t landed
        } else {
            asm volatile("s_waitcnt vmcnt(0)" ::: "memory");
        }
        __builtin_amdgcn_s_barrier();
        #pragma unroll
        for (int ks = 0; ks < 4; ks++) {
            const int sg = ks*2 + h;            // logical k-seg 0..7
            bf16x8 a[2], a2[2], b[2];
            #pragma unroll
            for (int i = 0; i < 2; i++) {
                const int q = wr*64 + i*32 + l31;          // H row
                a[i]  = *(const bf16x8*)&AS[buf][q][(sg ^ (q & 15)) * 8];
                a2[i] = sq_bf16x8(a[i]);
            }
            #pragma unroll
            for (int j = 0; j < 2; j++) {
                const int q = wc*64 + j*32 + l31;          // S row
                b[j] = *(const bf16x8*)&AS[buf][q][((8 + sg) ^ (q & 15)) * 8];
            }
            #pragma unroll
            for (int i = 0; i < 2; i++)
                #pragma unroll
                for (int j = 0; j < 2; j++) {
                    am[i][j] = MFMA32(a[i],  b[j], am[i][j], 0, 0, 0);
                    aq[i][j] = MFMA32(a2[i], b[j], aq[i][j], 0, 0, 0);
                }
        }
        __builtin_amdgcn_s_barrier();      // reads done -> next issue may reuse buf
        buf ^= 1;
    }
    #undef PV_STAGE

    // ---- epilogue: per c-half i, stage sd/mean in freed AS, then coalesce.
    // acc C layout (32x32): col n = wc*64 + j*32 + l31,
    // row c = c0 + wr*64 + i*32 + 8*qd + 4*h + r2.
    // LDS row index sc = wr*32 + (8*qd + 4*h + r2); c = (sc>>5)*64 + i*32 + (sc&31).
    float* Lsd = (float*)&AS[0][0][0];     // [64][128] f32, 32 KB
    float* Lmn = (float*)&AS[1][0][0];     // [64][128] f32, 32 KB
    const int nbase = strip_base + nl0;
    float inv2[2];
    #pragma unroll
    for (int j = 0; j < 2; j++)
        inv2[j] = 1.f / (rs[nbase + wc*64 + j*32 + l31] + EPSN);

    #pragma unroll
    for (int i = 0; i < 2; i++) {
        if (i) __builtin_amdgcn_s_barrier();   // prior store pass done
        #pragma unroll
        for (int j = 0; j < 2; j++) {
            const int n = wc*64 + j*32 + l31;
            const float inv = inv2[j];
            #pragma unroll
            for (int qd = 0; qd < 4; qd++) {
                #pragma unroll
                for (int r2 = 0; r2 < 4; r2++) {
                    const int reg = qd*4 + r2;
                    float mean = am[i][j][reg] * inv;
                    float msq  = aq[i][j][reg] * inv;
                    float sd   = sqrtf(fmaxf(msq - mean*mean, 0.f));
                    const int sc = wr*32 + 8*qd + 4*h + r2;
                    Lsd[sc*128 + n] = sd;
                    Lmn[sc*128 + n] = mean;
                }
            }
        }
        __builtin_amdgcn_s_barrier();
        #pragma unroll
        for (int p = 0; p < 8; p++) {
            const int row = p*8 + (t >> 5);            // sc 0..63
            const int col = (t & 31) * 4;              // n 0..124
            const int c   = c0 + ((row >> 5) * 64) + i*32 + (row & 31);
            float4 sd4 = *(const float4*)&Lsd[row*128 + col];
            float4 mn4 = *(const float4*)&Lmn[row*128 + col];
            const float muc = mu[c], isc = isd[c];
            float4 cv = *(const float4*)&content_b[(size_t)c * NPIX + nbase + col];
            float4 o;
            o.x = sd4.x * (cv.x - muc) * isc + mn4.x;
            o.y = sd4.y * (cv.y - muc) * isc + mn4.y;
            o.z = sd4.z * (cv.z - muc) * isc + mn4.z;
            o.w = sd4.w * (cv.w - muc) * isc + mn4.w;
            *(float4*)&out_b[(size_t)c * NPIX + nbase + col] = o;
        }
    }
}

// ---------------------------------------------------------------------------
// content_stats: per (b,c) mean and 1/std (unbiased var, +1e-5), fp32 input
// ---------------------------------------------------------------------------
__global__ __launch_bounds__(256) void content_stats(const float* __restrict__ x,
    float* __restrict__ mu, float* __restrict__ isd)
{
    const int bc = blockIdx.x;
    const int tid = threadIdx.x;
    const float* row = x + (size_t)bc * NPIX;
    float s = 0.f, s2 = 0.f;
    for (int i = tid * 4; i < NPIX; i += 256 * 4) {
        float4 v = *(const float4*)&row[i];
        s  += v.x + v.y + v.z + v.w;
        s2 += v.x*v.x + v.y*v.y + v.z*v.z + v.w*v.w;
    }
    __shared__ float r1[256], r2[256];
    r1[tid] = s; r2[tid] = s2; __syncthreads();
    for (int st = 128; st; st >>= 1) {
        if (tid < st) { r1[tid] += r1[tid+st]; r2[tid] += r2[tid+st]; }
        __syncthreads();
    }
    if (tid == 0) {
        float m = r1[0] / NPIX;
        float var = (r2[0] - (float)NPIX * m * m) / (float)(NPIX - 1);
        mu[bc]  = m;
        isd[bc] = rsqrtf(var + 1e-5f);
    }
}

// ---------------------------------------------------------------------------
extern "C" void kernel_launch(void* const* d_in, const int* in_sizes, int n_in,
                              void* d_out, int out_size, void* d_ws, size_t ws_size,
                              hipStream_t stream)
{
    const float* content     = (const float*)d_in[0];
    const float* style       = (const float*)d_in[1];
    const float* content_key = (const float*)d_in[2];
    const float* style_key   = (const float*)d_in[3];
    const float* Wf  = (const float*)d_in[4];
    const float* bf_ = (const float*)d_in[5];
    const float* Wg  = (const float*)d_in[6];
    const float* bg  = (const float*)d_in[7];
    const float* Wh  = (const float*)d_in[8];
    const float* bh  = (const float*)d_in[9];
    float* out = (float*)d_out;

    const size_t TB = (size_t)CDIM * NPIX;   // elems per batch-tensor
    const size_t tail_bytes = (3 * (size_t)B_SZ * NPIX + 2 * (size_t)B_SZ * CDIM) * 4 + 256;

    // choose (nb, ns): bytes = nb*(6*TB + NPIX*ns)*2 + tail
    int nb = 1, ns = 512;
    {
        const int nbc[5] = {4, 2, 4, 2, 1};
        const int nsc[5] = {4096, 4096, 2048, 2048, 4096};
        bool found = false;
        for (int i = 0; i < 5; i++) {
            size_t need = (size_t)nbc[i] * (6 * TB + (size_t)NPIX * nsc[i]) * 2 + tail_bytes;
            if (need <= ws_size) { nb = nbc[i]; ns = nsc[i]; found = true; break; }
        }
        if (!found) {
            nb = 1;
            for (int cand = 2048; cand >= 512; cand >>= 1) {
                size_t need = (6 * TB + (size_t)NPIX * cand) * 2 + tail_bytes;
                if (need <= ws_size) { ns = cand; break; }
            }
        }
    }
    const size_t s_stride = (size_t)NPIX * ns;   // elems per batch S strip

    u16* FT  = (u16*)d_ws;                   // nb x [NPIX][CDIM]
    u16* GT  = FT + (size_t)nb * TB;
    u16* Hb  = GT + (size_t)nb * TB;         // nb x [CDIM][NPIX]
    u16* XT  = Hb + (size_t)nb * TB;         // nb*3 x [NPIX][CDIM]
    u16* Sb  = XT + (size_t)nb * 3 * TB;     // nb x [ns][NPIX]
    float* Fn  = (float*)(Sb + (size_t)nb * s_stride);
    float* Gn  = Fn + (size_t)B_SZ * NPIX;
    float* rsb = Gn + (size_t)B_SZ * NPIX;
    float* mu  = rsb + (size_t)B_SZ * NPIX;
    float* isd = mu + (size_t)B_SZ * CDIM;

    content_stats<<<B_SZ * CDIM, 256, 0, stream>>>(content, mu, isd);

    const int sg_swz = ((ns / 128) % 8 == 0) ? 1 : 0;
    const int sg_blocks = (NPIX / 128) * (ns / 128);
    const int pv_blocks = (CDIM / 128) * (ns / 128);
    const int pv_swz = (pv_blocks % 8 == 0) ? 1 : 0;

    for (int bg0 = 0; bg0 < B_SZ; bg0 += nb) {
        const int g = (bg0 + nb <= B_SZ) ? nb : (B_SZ - bg0);

        transpose3b<<<dim3(NPIX/64, CDIM/64, 3*g), 256, 0, stream>>>(
                content_key, style_key, style, XT, bg0);

        conv3b<<<dim3(NPIX/64, CDIM/64, 3*g), 256, 0, stream>>>(
                XT, Wf, Wg, Wh, bf_, bg, bh, FT, GT, Hb);

        norm2b<<<dim3(NPIX/256, 2*g), 256, 0, stream>>>(FT, GT, Fn, Gn, rsb);

        for (int s0 = 0; s0 < NPIX; s0 += ns) {
            s_gemm128<<<dim3(sg_blocks, g), 256, 0, stream>>>(FT, GT, Fn, Gn,
                    Sb, rsb, s0, sg_swz, s_stride);
            pv128<<<dim3(pv_blocks, g), 256, 0, stream>>>(Hb, Sb, rsb,
                    content, mu, isd, out, s0, bg0, s_stride, pv_swz);
        }
    }
}